// Round 4
// baseline (813.250 us; speedup 1.0000x reference)
//
#include <hip/hip_runtime.h>

typedef __attribute__((ext_vector_type(8))) short short8;
typedef __attribute__((ext_vector_type(4))) float f32x4;

constexpr int B_ = 4, S_ = 2048, E_ = 1024, H_ = 8, D_ = 256;
constexpr int HD_ = H_ * D_;   // 2048
constexpr int BS_ = B_ * S_;   // 8192
constexpr int BH_ = B_ * H_;   // 32
constexpr float INV_SQRT_E = 0.03125f;  // 1/sqrt(1024)

__device__ __forceinline__ unsigned short f2bf(float f) {
    union { float f; unsigned u; } x; x.f = f;
    unsigned r = (x.u + 0x7fffu + ((x.u >> 16) & 1u)) >> 16;
    return (unsigned short)r;
}

__device__ __forceinline__ void gl_lds16(const void* g, void* lds) {
    __builtin_amdgcn_global_load_lds((const __attribute__((address_space(1))) void*)g,
                                     (__attribute__((address_space(3))) void*)lds, 16, 0, 0);
}

// ---------------- cast A fp32 -> bf16 (vectorized) ----------------
__global__ __launch_bounds__(256) void cast_k(const float* __restrict__ src,
                                              unsigned short* __restrict__ dst, int n4) {
    int i = blockIdx.x * 256 + threadIdx.x;
    if (i >= n4) return;
    float4 v = reinterpret_cast<const float4*>(src)[i];
    ushort4 o;
    o.x = f2bf(v.x); o.y = f2bf(v.y); o.z = f2bf(v.z); o.w = f2bf(v.w);
    reinterpret_cast<ushort4*>(dst)[i] = o;
}

// ------------- batched transpose+cast: (bt,R,C) f32 -> (bt,C,R) bf16 -------------
__global__ __launch_bounds__(256) void tcast_k(const float* __restrict__ src,
                                               unsigned short* __restrict__ dst, int R, int C) {
    __shared__ float tile[32][33];
    int b = blockIdx.z;
    const float* s = src + (size_t)b * R * C;
    unsigned short* d = dst + (size_t)b * R * C;
    int c0 = blockIdx.x * 32, r0 = blockIdx.y * 32;
    int tx = threadIdx.x, ty = threadIdx.y;
#pragma unroll
    for (int i = 0; i < 4; ++i)
        tile[ty + i * 8][tx] = s[(size_t)(r0 + ty + i * 8) * C + c0 + tx];
    __syncthreads();
#pragma unroll
    for (int i = 0; i < 4; ++i)
        d[(size_t)(c0 + ty + i * 8) * R + r0 + tx] = f2bf(tile[tx][ty + i * 8]);
}

// ------------- bf16 transpose: (BH,S,D) -> (BH,D,S) -------------
__global__ __launch_bounds__(256) void tbf_k(const unsigned short* __restrict__ src,
                                             unsigned short* __restrict__ dst) {
    __shared__ unsigned short tile[32][33];
    int bh = blockIdx.z;
    int d0 = blockIdx.x * 32, s0 = blockIdx.y * 32;
    int tx = threadIdx.x, ty = threadIdx.y;
#pragma unroll
    for (int i = 0; i < 4; ++i)
        tile[ty + i * 8][tx] = src[((size_t)bh * S_ + s0 + ty + i * 8) * D_ + d0 + tx];
    __syncthreads();
#pragma unroll
    for (int i = 0; i < 4; ++i)
        dst[((size_t)bh * D_ + d0 + ty + i * 8) * S_ + s0 + tx] = tile[tx][ty + i * 8];
}

// ------------- QKV GEMM: A(BS,E) x Wt(n)[k] -> relu(+bias) -> (B,H,S,D) bf16 -------------
__global__ __launch_bounds__(256) void gemm_qkv_k(const unsigned short* __restrict__ A,
                                                  const unsigned short* __restrict__ Bt,
                                                  const float* __restrict__ bias,
                                                  unsigned short* __restrict__ out) {
    __shared__ __align__(16) unsigned short As[128 * 32];
    __shared__ __align__(16) unsigned short Bs[128 * 32];
    const int tid = threadIdx.x;
    const int wave = tid >> 6, lane = tid & 63;
    const int quad = lane >> 4, l15 = lane & 15;
    const int wm = wave >> 1, wn = wave & 1;
    const int m0 = blockIdx.y * 128, n0 = blockIdx.x * 128;
    const int c1 = tid, c2 = tid + 256;
    const int r1 = c1 >> 2, kc1 = (c1 & 3) * 8;
    const int r2 = c2 >> 2, kc2 = (c2 & 3) * 8;
    char* aB1 = (char*)As + wave * 1024; char* aB2 = aB1 + 4096;
    char* bB1 = (char*)Bs + wave * 1024; char* bB2 = bB1 + 4096;
    const unsigned short* a1 = A + (size_t)(m0 + r1) * E_ + kc1;
    const unsigned short* a2 = A + (size_t)(m0 + r2) * E_ + kc2;
    const unsigned short* b1 = Bt + (size_t)(n0 + r1) * E_ + kc1;
    const unsigned short* b2 = Bt + (size_t)(n0 + r2) * E_ + kc2;
    f32x4 acc[4][4] = {};
    for (int k0 = 0; k0 < E_; k0 += 32) {
        __syncthreads();
        gl_lds16(a1 + k0, aB1);
        gl_lds16(a2 + k0, aB2);
        gl_lds16(b1 + k0, bB1);
        gl_lds16(b2 + k0, bB2);
        __syncthreads();
        short8 af[4], bf[4];
        const short* Ass = (const short*)As;
        const short* Bss = (const short*)Bs;
#pragma unroll
        for (int f = 0; f < 4; ++f) {
            af[f] = *(const short8*)&Ass[(wm * 64 + f * 16 + l15) * 32 + quad * 8];
            bf[f] = *(const short8*)&Bss[(wn * 64 + f * 16 + l15) * 32 + quad * 8];
        }
#pragma unroll
        for (int fm = 0; fm < 4; ++fm)
#pragma unroll
            for (int fn = 0; fn < 4; ++fn)
                acc[fm][fn] = __builtin_amdgcn_mfma_f32_16x16x32_bf16(af[fm], bf[fn], acc[fm][fn], 0, 0, 0);
    }
#pragma unroll
    for (int fm = 0; fm < 4; ++fm) {
        int mbase = m0 + wm * 64 + fm * 16 + quad * 4;
#pragma unroll
        for (int fn = 0; fn < 4; ++fn) {
            int n = n0 + wn * 64 + fn * 16 + l15;
            int h = n >> 8, d = n & 255;
            float bv = bias[n];
#pragma unroll
            for (int r = 0; r < 4; ++r) {
                int m = mbase + r;
                int b = m >> 11, s = m & 2047;
                float v = fmaxf(acc[fm][fn][r] + bv, 0.0f);
                out[((size_t)(b * H_ + h) * S_ + s) * D_ + d] = f2bf(v);
            }
        }
    }
}

// ------------- output GEMM: Zall(BS,HD) x Wzt(n)[k] + bZ -> fp32 (BS,E) -------------
__global__ __launch_bounds__(256) void gemm_out_k(const unsigned short* __restrict__ A,
                                                  const unsigned short* __restrict__ Bt,
                                                  const float* __restrict__ bias,
                                                  float* __restrict__ out) {
    __shared__ __align__(16) unsigned short As[128 * 32];
    __shared__ __align__(16) unsigned short Bs[128 * 32];
    const int tid = threadIdx.x;
    const int wave = tid >> 6, lane = tid & 63;
    const int quad = lane >> 4, l15 = lane & 15;
    const int wm = wave >> 1, wn = wave & 1;
    const int m0 = blockIdx.y * 128, n0 = blockIdx.x * 128;
    const int c1 = tid, c2 = tid + 256;
    const int r1 = c1 >> 2, kc1 = (c1 & 3) * 8;
    const int r2 = c2 >> 2, kc2 = (c2 & 3) * 8;
    char* aB1 = (char*)As + wave * 1024; char* aB2 = aB1 + 4096;
    char* bB1 = (char*)Bs + wave * 1024; char* bB2 = bB1 + 4096;
    const unsigned short* a1 = A + (size_t)(m0 + r1) * HD_ + kc1;
    const unsigned short* a2 = A + (size_t)(m0 + r2) * HD_ + kc2;
    const unsigned short* b1 = Bt + (size_t)(n0 + r1) * HD_ + kc1;
    const unsigned short* b2 = Bt + (size_t)(n0 + r2) * HD_ + kc2;
    f32x4 acc[4][4] = {};
    for (int k0 = 0; k0 < HD_; k0 += 32) {
        __syncthreads();
        gl_lds16(a1 + k0, aB1);
        gl_lds16(a2 + k0, aB2);
        gl_lds16(b1 + k0, bB1);
        gl_lds16(b2 + k0, bB2);
        __syncthreads();
        short8 af[4], bf[4];
        const short* Ass = (const short*)As;
        const short* Bss = (const short*)Bs;
#pragma unroll
        for (int f = 0; f < 4; ++f) {
            af[f] = *(const short8*)&Ass[(wm * 64 + f * 16 + l15) * 32 + quad * 8];
            bf[f] = *(const short8*)&Bss[(wn * 64 + f * 16 + l15) * 32 + quad * 8];
        }
#pragma unroll
        for (int fm = 0; fm < 4; ++fm)
#pragma unroll
            for (int fn = 0; fn < 4; ++fn)
                acc[fm][fn] = __builtin_amdgcn_mfma_f32_16x16x32_bf16(af[fm], bf[fn], acc[fm][fn], 0, 0, 0);
    }
#pragma unroll
    for (int fm = 0; fm < 4; ++fm) {
        int mbase = m0 + wm * 64 + fm * 16 + quad * 4;
#pragma unroll
        for (int fn = 0; fn < 4; ++fn) {
            int n = n0 + wn * 64 + fn * 16 + l15;
            float bv = bias[n];
#pragma unroll
            for (int r = 0; r < 4; ++r)
                out[(size_t)(mbase + r) * E_ + n] = acc[fm][fn][r] + bv;
        }
    }
}

// ======== colsum_k v4: TBLK=128, XCD-affine mapping. Physical block p runs on
// XCD p%8 (round-robin dispatch); map so each XCD owns heads {x, x+8, x+16, x+24}
// with the 2-head concurrent working set (Q 2MB) L2-resident. K-frags in regs,
// qf prefetch, zero LDS in s-loop. ========
__global__ __launch_bounds__(512, 2) void colsum_k(const unsigned short* __restrict__ Q,
                                                   const unsigned short* __restrict__ K,
                                                   float* __restrict__ invLcol) {
    __shared__ float part[8][64];
    const int tid = threadIdx.x;
    const int wave = tid >> 6, lane = tid & 63;
    const int quad = lane >> 4, l15 = lane & 15;
    const int tg = wave >> 2, sg = wave & 3;
    const int p = blockIdx.x;
    const int bh = (p & 7) + 8 * ((p >> 3) >> 4);   // head locked to XCD p%8
    const int t0 = ((p >> 3) & 15) * 128;
    const unsigned short* Qh = Q + (size_t)bh * S_ * D_;
    const unsigned short* Kh = K + (size_t)bh * S_ * D_;
    // K fragments for this wave's 64 t-rows: 32 x short8 = 128 VGPR
    short8 kf[32];
#pragma unroll
    for (int kc = 0; kc < 8; ++kc)
#pragma unroll
        for (int fm = 0; fm < 4; ++fm)
            kf[kc * 4 + fm] = *(const short8*)&Kh[(size_t)(t0 + tg * 64 + fm * 16 + l15) * D_ + kc * 32 + quad * 8];
    float rl[4][4] = {};
    const unsigned short* Qw = Qh + (size_t)(sg * 16 + l15) * D_ + quad * 8;
    short8 qf[8];
#pragma unroll
    for (int kc = 0; kc < 8; ++kc) qf[kc] = *(const short8*)&Qw[kc * 32];
    for (int s0 = 0; s0 < S_; s0 += 64) {
        f32x4 acc[4] = {};
#pragma unroll
        for (int kc = 0; kc < 8; ++kc)
#pragma unroll
            for (int fm = 0; fm < 4; ++fm)
                acc[fm] = __builtin_amdgcn_mfma_f32_16x16x32_bf16(kf[kc * 4 + fm], qf[kc], acc[fm], 0, 0, 0);
        // prefetch next s-step (wraps harmlessly on last iter)
        int sn = (s0 + 64) & (S_ - 1);
#pragma unroll
        for (int kc = 0; kc < 8; ++kc)
            qf[kc] = *(const short8*)&Qw[(size_t)sn * D_ + kc * 32];
#pragma unroll
        for (int fm = 0; fm < 4; ++fm)
#pragma unroll
            for (int r = 0; r < 4; ++r)
                rl[fm][r] += __expf(acc[fm][r] * INV_SQRT_E);
    }
#pragma unroll
    for (int fm = 0; fm < 4; ++fm)
#pragma unroll
        for (int r = 0; r < 4; ++r) {
            float v = rl[fm][r];
            v += __shfl_xor(v, 1); v += __shfl_xor(v, 2);
            v += __shfl_xor(v, 4); v += __shfl_xor(v, 8);
            if (l15 == 0) part[wave][fm * 16 + quad * 4 + r] = v;
        }
    __syncthreads();
    if (tid < 128) {
        int tg2 = tid >> 6, i = tid & 63;
        float s = part[tg2 * 4 + 0][i] + part[tg2 * 4 + 1][i] +
                  part[tg2 * 4 + 2][i] + part[tg2 * 4 + 3][i];
        invLcol[(size_t)bh * S_ + t0 + tid] = 1.0f / s;
    }
}

// ======== flash9_k: QBLK=128 + XCD-affine mapping (K/V of the 2 concurrent heads
// per XCD fit its 4MB L2 -> loads become L2 hits, not L3 streams).
// Q per-wave in REGISTERS (no Qs LDS: kills the 2.2e7 bank-conflict spike and the
// staging phase). LDS = Ps 40KB only. kb rolling-2; vb kk=0 pre-barrier prefetch.
// Unified regs ~250 (q128 + zacc64 + acc16 + rsacc16 + kb8 + vb16) @ 2 waves/SIMD. ========
__global__ __launch_bounds__(512, 2) void flash9_k(const unsigned short* __restrict__ Q,
                                                   const unsigned short* __restrict__ K,
                                                   const unsigned short* __restrict__ Vt,
                                                   const float* __restrict__ invLcol,
                                                   unsigned short* __restrict__ Zall) {
    __shared__ __align__(16) unsigned short Ps[2 * 2 * 128 * 40];  // 40 KB, double-buffered
    __shared__ float rsum[128];
    const int tid = threadIdx.x;
    const int wave = tid >> 6, lane = tid & 63;
    const int quad = lane >> 4, l15 = lane & 15;
    const int rg = wave >> 2, tc = wave & 3;  // QK roles: row-group of 64, t-cols of 16
    const int dc = wave & 3;                  // PV role: d-cols of 64
    const int p = blockIdx.x;
    const int bh = (p & 7) + 8 * ((p >> 3) >> 4);   // head locked to XCD p%8
    const int s0 = ((p >> 3) & 15) * 128;
    const int bb = bh >> 3, hh = bh & 7;
    const unsigned short* Qh = Q + (size_t)bh * S_ * D_;
    const unsigned short* Kh = K + (size_t)bh * S_ * D_;
    const unsigned short* Vh = Vt + (size_t)bh * D_ * S_;
    const float* Lc = invLcol + (size_t)bh * S_;

    // Q fragments for this wave's 64 rows (loaded once; tc-waves share rows via L2)
    short8 q[32];
#pragma unroll
    for (int kc = 0; kc < 8; ++kc)
#pragma unroll
        for (int fm = 0; fm < 4; ++fm)
            q[kc * 4 + fm] = *(const short8*)&Qh[(size_t)(s0 + rg * 64 + fm * 16 + l15) * D_ + kc * 32 + quad * 8];

    if (tid < 128) rsum[tid] = 0.f;
    f32x4 zacc[4][4] = {};
    float rsacc[4][4] = {};

    const char* KtBase = (const char*)(Kh + (size_t)(tc * 16 + l15) * D_ + quad * 8);
    const char* VwBase = (const char*)(Vh + (size_t)(dc * 64 + l15) * S_ + quad * 8);
    float Li = Lc[tc * 16 + l15];
    short8 kb[2];
    kb[0] = *(const short8*)(KtBase + 0 * 64);
    kb[1] = *(const short8*)(KtBase + 1 * 64);

    for (int t0 = 0; t0 < S_; t0 += 64) {
        const int buf = (t0 >> 6) & 1;
        const int tn = (t0 + 64) & (S_ - 1);  // prefetch target (wraps harmlessly)
        // ---- QK: rows rg*64..+63, cols t0+tc*16..+15; Q from regs, K rolling-2 ----
        f32x4 acc[4] = {};
#pragma unroll
        for (int kc = 0; kc < 8; ++kc) {
            short8 kbu = kb[kc & 1];
            if (kc < 6)
                kb[kc & 1] = *(const short8*)(KtBase + (size_t)t0 * (D_ * 2) + (kc + 2) * 64);
            else
                kb[kc & 1] = *(const short8*)(KtBase + (size_t)tn * (D_ * 2) + (kc - 6) * 64);
#pragma unroll
            for (int fm = 0; fm < 4; ++fm)
                acc[fm] = __builtin_amdgcn_mfma_f32_16x16x32_bf16(q[kc * 4 + fm], kbu, acc[fm], 0, 0, 0);
        }
        float Li_n = Lc[tn + tc * 16 + l15];
        // ---- P = exp(exp(sc)*invL) -> Ps[buf] ----
        unsigned short* Pw = Ps + buf * 10240 + (tc >> 1) * 5120 + (tc & 1) * 16 + l15;
#pragma unroll
        for (int fm = 0; fm < 4; ++fm)
#pragma unroll
            for (int r = 0; r < 4; ++r) {
                float e = __expf(__expf(acc[fm][r] * INV_SQRT_E) * Li);
                rsacc[fm][r] += e;
                int row = rg * 64 + fm * 16 + quad * 4 + r;
                Pw[row * 40] = f2bf(e);
            }
        // ---- prefetch vb kk=0 (overlaps barrier wait) ----
        short8 vb[4];
#pragma unroll
        for (int fn = 0; fn < 4; ++fn)
            vb[fn] = *(const short8*)(VwBase + ((size_t)(fn * 16) * S_ + t0) * 2);
        __syncthreads();
        // ---- PV kk=0 ----
        short8 pa[4];
#pragma unroll
        for (int fm = 0; fm < 4; ++fm)
            pa[fm] = *(const short8*)&Ps[buf * 10240 + (rg * 64 + fm * 16 + l15) * 40 + quad * 8];
#pragma unroll
        for (int fm = 0; fm < 4; ++fm)
#pragma unroll
            for (int fn = 0; fn < 4; ++fn)
                zacc[fm][fn] = __builtin_amdgcn_mfma_f32_16x16x32_bf16(pa[fm], vb[fn], zacc[fm][fn], 0, 0, 0);
        // ---- PV kk=1 (vb reloaded into same regs) ----
#pragma unroll
        for (int fn = 0; fn < 4; ++fn)
            vb[fn] = *(const short8*)(VwBase + ((size_t)(fn * 16) * S_ + t0 + 32) * 2);
#pragma unroll
        for (int fm = 0; fm < 4; ++fm)
            pa[fm] = *(const short8*)&Ps[buf * 10240 + 5120 + (rg * 64 + fm * 16 + l15) * 40 + quad * 8];
#pragma unroll
        for (int fm = 0; fm < 4; ++fm)
#pragma unroll
            for (int fn = 0; fn < 4; ++fn)
                zacc[fm][fn] = __builtin_amdgcn_mfma_f32_16x16x32_bf16(pa[fm], vb[fn], zacc[fm][fn], 0, 0, 0);
        Li = Li_n;
    }
    // ---- rowsum reduce: wave (rg,tc) holds partials for rows rg*64+.. over its t-cols ----
#pragma unroll
    for (int fm = 0; fm < 4; ++fm)
#pragma unroll
        for (int r = 0; r < 4; ++r) {
            float v = rsacc[fm][r];
            v += __shfl_xor(v, 1); v += __shfl_xor(v, 2);
            v += __shfl_xor(v, 4); v += __shfl_xor(v, 8);
            if (l15 == 0) atomicAdd(&rsum[rg * 64 + fm * 16 + quad * 4 + r], v);
        }
    __syncthreads();
#pragma unroll
    for (int fm = 0; fm < 4; ++fm)
#pragma unroll
        for (int r = 0; r < 4; ++r) {
            int row = rg * 64 + fm * 16 + quad * 4 + r;
            float inv = 1.0f / rsum[row];
#pragma unroll
            for (int fn = 0; fn < 4; ++fn)
                Zall[(size_t)(bb * S_ + s0 + row) * HD_ + hh * D_ + dc * 64 + fn * 16 + l15] =
                    f2bf(zacc[fm][fn][r] * inv);
        }
}

extern "C" void kernel_launch(void* const* d_in, const int* in_sizes, int n_in,
                              void* d_out, int out_size, void* d_ws, size_t ws_size,
                              hipStream_t stream) {
    const float* Ain = (const float*)d_in[0];
    const float* WQ = (const float*)d_in[1];
    const float* bQ = (const float*)d_in[2];
    const float* WK = (const float*)d_in[3];
    const float* bK = (const float*)d_in[4];
    const float* WV = (const float*)d_in[5];
    const float* bV = (const float*)d_in[6];
    const float* WZ = (const float*)d_in[7];
    const float* bZ = (const float*)d_in[8];
    float* out = (float*)d_out;

    char* ws = (char*)d_ws;
    size_t off = 0;
    auto alloc = [&](size_t bytes) {
        char* p = ws + off;
        off += (bytes + 255) & ~(size_t)255;
        return p;
    };
    unsigned short* Abf = (unsigned short*)alloc((size_t)BS_ * E_ * 2);
    unsigned short* Wqt = (unsigned short*)alloc((size_t)H_ * D_ * E_ * 2);
    unsigned short* Wkt = (unsigned short*)alloc((size_t)H_ * D_ * E_ * 2);
    unsigned short* Wvt = (unsigned short*)alloc((size_t)H_ * D_ * E_ * 2);
    unsigned short* Wzt = (unsigned short*)alloc((size_t)E_ * HD_ * 2);
    unsigned short* Qb = (unsigned short*)alloc((size_t)BH_ * S_ * D_ * 2);
    unsigned short* Kb = (unsigned short*)alloc((size_t)BH_ * S_ * D_ * 2);
    unsigned short* Vb = (unsigned short*)alloc((size_t)BH_ * S_ * D_ * 2);
    unsigned short* Vtb = (unsigned short*)alloc((size_t)BH_ * S_ * D_ * 2);
    unsigned short* Zb = (unsigned short*)alloc((size_t)BS_ * HD_ * 2);
    float* Lc = (float*)alloc((size_t)BH_ * S_ * 4);

    dim3 tb(32, 8);
    cast_k<<<(BS_ * E_ / 4 + 255) / 256, 256, 0, stream>>>(Ain, Abf, BS_ * E_ / 4);
    tcast_k<<<dim3(D_ / 32, E_ / 32, H_), tb, 0, stream>>>(WQ, Wqt, E_, D_);
    tcast_k<<<dim3(D_ / 32, E_ / 32, H_), tb, 0, stream>>>(WK, Wkt, E_, D_);
    tcast_k<<<dim3(D_ / 32, E_ / 32, H_), tb, 0, stream>>>(WV, Wvt, E_, D_);
    tcast_k<<<dim3(E_ / 32, HD_ / 32, 1), tb, 0, stream>>>(WZ, Wzt, HD_, E_);

    gemm_qkv_k<<<dim3(HD_ / 128, BS_ / 128), 256, 0, stream>>>(Abf, Wqt, bQ, Qb);
    gemm_qkv_k<<<dim3(HD_ / 128, BS_ / 128), 256, 0, stream>>>(Abf, Wkt, bK, Kb);
    gemm_qkv_k<<<dim3(HD_ / 128, BS_ / 128), 256, 0, stream>>>(Abf, Wvt, bV, Vb);

    tbf_k<<<dim3(D_ / 32, S_ / 32, BH_), tb, 0, stream>>>(Vb, Vtb);

    colsum_k<<<dim3(BH_ * S_ / 128), 512, 0, stream>>>(Qb, Kb, Lc);
    flash9_k<<<dim3(BH_ * S_ / 128), 512, 0, stream>>>(Qb, Kb, Vtb, Lc, Zb);

    gemm_out_k<<<dim3(E_ / 128, BS_ / 128), 256, 0, stream>>>(Zb, Wzt, bZ, out);
}

// Round 5
// 723.751 us; speedup vs baseline: 1.1237x; 1.1237x over previous
//
#include <hip/hip_runtime.h>

typedef __attribute__((ext_vector_type(8))) short short8;
typedef __attribute__((ext_vector_type(4))) float f32x4;

constexpr int B_ = 4, S_ = 2048, E_ = 1024, H_ = 8, D_ = 256;
constexpr int HD_ = H_ * D_;   // 2048
constexpr int BS_ = B_ * S_;   // 8192
constexpr int BH_ = B_ * H_;   // 32
constexpr float INV_SQRT_E = 0.03125f;  // 1/sqrt(1024)

__device__ __forceinline__ unsigned short f2bf(float f) {
    union { float f; unsigned u; } x; x.f = f;
    unsigned r = (x.u + 0x7fffu + ((x.u >> 16) & 1u)) >> 16;
    return (unsigned short)r;
}

__device__ __forceinline__ void gl_lds16(const void* g, void* lds) {
    __builtin_amdgcn_global_load_lds((const __attribute__((address_space(1))) void*)g,
                                     (__attribute__((address_space(3))) void*)lds, 16, 0, 0);
}

// ---------------- cast A fp32 -> bf16 (vectorized) ----------------
__global__ __launch_bounds__(256) void cast_k(const float* __restrict__ src,
                                              unsigned short* __restrict__ dst, int n4) {
    int i = blockIdx.x * 256 + threadIdx.x;
    if (i >= n4) return;
    float4 v = reinterpret_cast<const float4*>(src)[i];
    ushort4 o;
    o.x = f2bf(v.x); o.y = f2bf(v.y); o.z = f2bf(v.z); o.w = f2bf(v.w);
    reinterpret_cast<ushort4*>(dst)[i] = o;
}

// ------------- batched transpose+cast: (bt,R,C) f32 -> (bt,C,R) bf16 -------------
__global__ __launch_bounds__(256) void tcast_k(const float* __restrict__ src,
                                               unsigned short* __restrict__ dst, int R, int C) {
    __shared__ float tile[32][33];
    int b = blockIdx.z;
    const float* s = src + (size_t)b * R * C;
    unsigned short* d = dst + (size_t)b * R * C;
    int c0 = blockIdx.x * 32, r0 = blockIdx.y * 32;
    int tx = threadIdx.x, ty = threadIdx.y;
#pragma unroll
    for (int i = 0; i < 4; ++i)
        tile[ty + i * 8][tx] = s[(size_t)(r0 + ty + i * 8) * C + c0 + tx];
    __syncthreads();
#pragma unroll
    for (int i = 0; i < 4; ++i)
        d[(size_t)(c0 + ty + i * 8) * R + r0 + tx] = f2bf(tile[tx][ty + i * 8]);
}

// ------------- bf16 transpose: (BH,S,D) -> (BH,D,S) -------------
__global__ __launch_bounds__(256) void tbf_k(const unsigned short* __restrict__ src,
                                             unsigned short* __restrict__ dst) {
    __shared__ unsigned short tile[32][33];
    int bh = blockIdx.z;
    int d0 = blockIdx.x * 32, s0 = blockIdx.y * 32;
    int tx = threadIdx.x, ty = threadIdx.y;
#pragma unroll
    for (int i = 0; i < 4; ++i)
        tile[ty + i * 8][tx] = src[((size_t)bh * S_ + s0 + ty + i * 8) * D_ + d0 + tx];
    __syncthreads();
#pragma unroll
    for (int i = 0; i < 4; ++i)
        dst[((size_t)bh * D_ + d0 + ty + i * 8) * S_ + s0 + tx] = tile[tx][ty + i * 8];
}

// ------------- QKV GEMM: A(BS,E) x Wt(n)[k] -> relu(+bias) -> (B,H,S,D) bf16 -------------
__global__ __launch_bounds__(256) void gemm_qkv_k(const unsigned short* __restrict__ A,
                                                  const unsigned short* __restrict__ Bt,
                                                  const float* __restrict__ bias,
                                                  unsigned short* __restrict__ out) {
    __shared__ __align__(16) unsigned short As[128 * 32];
    __shared__ __align__(16) unsigned short Bs[128 * 32];
    const int tid = threadIdx.x;
    const int wave = tid >> 6, lane = tid & 63;
    const int quad = lane >> 4, l15 = lane & 15;
    const int wm = wave >> 1, wn = wave & 1;
    const int m0 = blockIdx.y * 128, n0 = blockIdx.x * 128;
    const int c1 = tid, c2 = tid + 256;
    const int r1 = c1 >> 2, kc1 = (c1 & 3) * 8;
    const int r2 = c2 >> 2, kc2 = (c2 & 3) * 8;
    char* aB1 = (char*)As + wave * 1024; char* aB2 = aB1 + 4096;
    char* bB1 = (char*)Bs + wave * 1024; char* bB2 = bB1 + 4096;
    const unsigned short* a1 = A + (size_t)(m0 + r1) * E_ + kc1;
    const unsigned short* a2 = A + (size_t)(m0 + r2) * E_ + kc2;
    const unsigned short* b1 = Bt + (size_t)(n0 + r1) * E_ + kc1;
    const unsigned short* b2 = Bt + (size_t)(n0 + r2) * E_ + kc2;
    f32x4 acc[4][4] = {};
    for (int k0 = 0; k0 < E_; k0 += 32) {
        __syncthreads();
        gl_lds16(a1 + k0, aB1);
        gl_lds16(a2 + k0, aB2);
        gl_lds16(b1 + k0, bB1);
        gl_lds16(b2 + k0, bB2);
        __syncthreads();
        short8 af[4], bf[4];
        const short* Ass = (const short*)As;
        const short* Bss = (const short*)Bs;
#pragma unroll
        for (int f = 0; f < 4; ++f) {
            af[f] = *(const short8*)&Ass[(wm * 64 + f * 16 + l15) * 32 + quad * 8];
            bf[f] = *(const short8*)&Bss[(wn * 64 + f * 16 + l15) * 32 + quad * 8];
        }
#pragma unroll
        for (int fm = 0; fm < 4; ++fm)
#pragma unroll
            for (int fn = 0; fn < 4; ++fn)
                acc[fm][fn] = __builtin_amdgcn_mfma_f32_16x16x32_bf16(af[fm], bf[fn], acc[fm][fn], 0, 0, 0);
    }
#pragma unroll
    for (int fm = 0; fm < 4; ++fm) {
        int mbase = m0 + wm * 64 + fm * 16 + quad * 4;
#pragma unroll
        for (int fn = 0; fn < 4; ++fn) {
            int n = n0 + wn * 64 + fn * 16 + l15;
            int h = n >> 8, d = n & 255;
            float bv = bias[n];
#pragma unroll
            for (int r = 0; r < 4; ++r) {
                int m = mbase + r;
                int b = m >> 11, s = m & 2047;
                float v = fmaxf(acc[fm][fn][r] + bv, 0.0f);
                out[((size_t)(b * H_ + h) * S_ + s) * D_ + d] = f2bf(v);
            }
        }
    }
}

// ------------- output GEMM: Zall(BS,HD) x Wzt(n)[k] + bZ -> fp32 (BS,E) -------------
__global__ __launch_bounds__(256) void gemm_out_k(const unsigned short* __restrict__ A,
                                                  const unsigned short* __restrict__ Bt,
                                                  const float* __restrict__ bias,
                                                  float* __restrict__ out) {
    __shared__ __align__(16) unsigned short As[128 * 32];
    __shared__ __align__(16) unsigned short Bs[128 * 32];
    const int tid = threadIdx.x;
    const int wave = tid >> 6, lane = tid & 63;
    const int quad = lane >> 4, l15 = lane & 15;
    const int wm = wave >> 1, wn = wave & 1;
    const int m0 = blockIdx.y * 128, n0 = blockIdx.x * 128;
    const int c1 = tid, c2 = tid + 256;
    const int r1 = c1 >> 2, kc1 = (c1 & 3) * 8;
    const int r2 = c2 >> 2, kc2 = (c2 & 3) * 8;
    char* aB1 = (char*)As + wave * 1024; char* aB2 = aB1 + 4096;
    char* bB1 = (char*)Bs + wave * 1024; char* bB2 = bB1 + 4096;
    const unsigned short* a1 = A + (size_t)(m0 + r1) * HD_ + kc1;
    const unsigned short* a2 = A + (size_t)(m0 + r2) * HD_ + kc2;
    const unsigned short* b1 = Bt + (size_t)(n0 + r1) * HD_ + kc1;
    const unsigned short* b2 = Bt + (size_t)(n0 + r2) * HD_ + kc2;
    f32x4 acc[4][4] = {};
    for (int k0 = 0; k0 < HD_; k0 += 32) {
        __syncthreads();
        gl_lds16(a1 + k0, aB1);
        gl_lds16(a2 + k0, aB2);
        gl_lds16(b1 + k0, bB1);
        gl_lds16(b2 + k0, bB2);
        __syncthreads();
        short8 af[4], bf[4];
        const short* Ass = (const short*)As;
        const short* Bss = (const short*)Bs;
#pragma unroll
        for (int f = 0; f < 4; ++f) {
            af[f] = *(const short8*)&Ass[(wm * 64 + f * 16 + l15) * 32 + quad * 8];
            bf[f] = *(const short8*)&Bss[(wn * 64 + f * 16 + l15) * 32 + quad * 8];
        }
#pragma unroll
        for (int fm = 0; fm < 4; ++fm)
#pragma unroll
            for (int fn = 0; fn < 4; ++fn)
                acc[fm][fn] = __builtin_amdgcn_mfma_f32_16x16x32_bf16(af[fm], bf[fn], acc[fm][fn], 0, 0, 0);
    }
#pragma unroll
    for (int fm = 0; fm < 4; ++fm) {
        int mbase = m0 + wm * 64 + fm * 16 + quad * 4;
#pragma unroll
        for (int fn = 0; fn < 4; ++fn) {
            int n = n0 + wn * 64 + fn * 16 + l15;
            float bv = bias[n];
#pragma unroll
            for (int r = 0; r < 4; ++r)
                out[(size_t)(mbase + r) * E_ + n] = acc[fm][fn][r] + bv;
        }
    }
}

// ======== colsum_k v4: TBLK=128, XCD-affine (head locked to XCD p%8; proven
// FETCH 288->60MB in r4). K-frags in regs, qf prefetch, zero LDS in s-loop. ========
__global__ __launch_bounds__(512, 2) void colsum_k(const unsigned short* __restrict__ Q,
                                                   const unsigned short* __restrict__ K,
                                                   float* __restrict__ invLcol) {
    __shared__ float part[8][64];
    const int tid = threadIdx.x;
    const int wave = tid >> 6, lane = tid & 63;
    const int quad = lane >> 4, l15 = lane & 15;
    const int tg = wave >> 2, sg = wave & 3;
    const int p = blockIdx.x;
    const int bh = (p & 7) + 8 * ((p >> 3) >> 4);   // head locked to XCD p%8
    const int t0 = ((p >> 3) & 15) * 128;
    const unsigned short* Qh = Q + (size_t)bh * S_ * D_;
    const unsigned short* Kh = K + (size_t)bh * S_ * D_;
    short8 kf[32];
#pragma unroll
    for (int kc = 0; kc < 8; ++kc)
#pragma unroll
        for (int fm = 0; fm < 4; ++fm)
            kf[kc * 4 + fm] = *(const short8*)&Kh[(size_t)(t0 + tg * 64 + fm * 16 + l15) * D_ + kc * 32 + quad * 8];
    float rl[4][4] = {};
    const unsigned short* Qw = Qh + (size_t)(sg * 16 + l15) * D_ + quad * 8;
    short8 qf[8];
#pragma unroll
    for (int kc = 0; kc < 8; ++kc) qf[kc] = *(const short8*)&Qw[kc * 32];
    for (int s0 = 0; s0 < S_; s0 += 64) {
        f32x4 acc[4] = {};
#pragma unroll
        for (int kc = 0; kc < 8; ++kc)
#pragma unroll
            for (int fm = 0; fm < 4; ++fm)
                acc[fm] = __builtin_amdgcn_mfma_f32_16x16x32_bf16(kf[kc * 4 + fm], qf[kc], acc[fm], 0, 0, 0);
        int sn = (s0 + 64) & (S_ - 1);
#pragma unroll
        for (int kc = 0; kc < 8; ++kc)
            qf[kc] = *(const short8*)&Qw[(size_t)sn * D_ + kc * 32];
#pragma unroll
        for (int fm = 0; fm < 4; ++fm)
#pragma unroll
            for (int r = 0; r < 4; ++r)
                rl[fm][r] += __expf(acc[fm][r] * INV_SQRT_E);
    }
#pragma unroll
    for (int fm = 0; fm < 4; ++fm)
#pragma unroll
        for (int r = 0; r < 4; ++r) {
            float v = rl[fm][r];
            v += __shfl_xor(v, 1); v += __shfl_xor(v, 2);
            v += __shfl_xor(v, 4); v += __shfl_xor(v, 8);
            if (l15 == 0) part[wave][fm * 16 + quad * 4 + r] = v;
        }
    __syncthreads();
    if (tid < 128) {
        int tg2 = tid >> 6, i = tid & 63;
        float s = part[tg2 * 4 + 0][i] + part[tg2 * 4 + 1][i] +
                  part[tg2 * 4 + 2][i] + part[tg2 * 4 + 3][i];
        invLcol[(size_t)bh * S_ + t0 + tid] = 1.0f / s;
    }
}

// ======== flash10_k: flash8 skeleton (Q in LDS -> no spill, VGPR ~104; kb[8]/vb[8]
// batched prefetch -> 8 outstanding loads) + XCD-affine mapping (r4-proven: FETCH
// 288->60MB) + Qs PADDED stride 136 shorts / 272B (read banks = 4*l15 mod 32:
// lanes 0-7 disjoint 32 banks, 8-15 alias 2-way = free; replaces broken XOR that
// spiked conflicts to 2.2e7). LDS 76.3KB -> 2 blocks/CU (4 waves/SIMD, 2x occ). ========
__global__ __launch_bounds__(512, 2) void flash10_k(const unsigned short* __restrict__ Q,
                                                    const unsigned short* __restrict__ K,
                                                    const unsigned short* __restrict__ Vt,
                                                    const float* __restrict__ invLcol,
                                                    unsigned short* __restrict__ Zall) {
    __shared__ __align__(16) unsigned short Qs[128 * 136];        // 34.8 KB, stride 272B
    __shared__ __align__(16) unsigned short Ps[2 * 2 * 128 * 40]; // 40 KB, double-buffered
    __shared__ float rsum[128];
    const int tid = threadIdx.x;
    const int wave = tid >> 6, lane = tid & 63;
    const int quad = lane >> 4, l15 = lane & 15;
    const int rg = wave >> 2, tc = wave & 3;  // QK roles: row-group of 64, t-cols of 16
    const int dc = wave & 3;                  // PV role: d-cols of 64
    const int p = blockIdx.x;
    const int bh = (p & 7) + 8 * ((p >> 3) >> 4);   // head locked to XCD p%8
    const int s0 = ((p >> 3) & 15) * 128;
    const int bb = bh >> 3, hh = bh & 7;
    const unsigned short* Qh = Q + (size_t)bh * S_ * D_;
    const unsigned short* Kh = K + (size_t)bh * S_ * D_;
    const unsigned short* Vh = Vt + (size_t)bh * D_ * S_;
    const float* Lc = invLcol + (size_t)bh * S_;

    // ---- stage Q -> Qs (padded rows, no swizzle) ----
    {
        int row = tid >> 2, cb = (tid & 3) * 128;
        const char* src = (const char*)(Qh + (size_t)(s0 + row) * D_) + cb;
        char* dst = (char*)Qs + row * 272 + cb;
#pragma unroll
        for (int i = 0; i < 8; ++i)
            *(short8*)(dst + i * 16) = *(const short8*)(src + i * 16);
    }
    if (tid < 128) rsum[tid] = 0.f;
    f32x4 zacc[4][4] = {};
    float rsacc[4][4] = {};

    // ---- prologue loads (tile 0) ----
    const char* KtBase = (const char*)(Kh + (size_t)(tc * 16 + l15) * D_ + quad * 8);
    const char* VwBase = (const char*)(Vh + (size_t)(dc * 64 + l15) * S_ + quad * 8);
    short8 kb[8], vb[8];
#pragma unroll
    for (int kc = 0; kc < 8; ++kc)
        kb[kc] = *(const short8*)(KtBase + kc * 64);
#pragma unroll
    for (int kk = 0; kk < 2; ++kk)
#pragma unroll
        for (int fn = 0; fn < 4; ++fn)
            vb[kk * 4 + fn] = *(const short8*)(VwBase + ((size_t)(fn * 16) * S_ + kk * 32) * 2);
    float Li = Lc[tc * 16 + l15];
    __syncthreads();  // Qs ready

    for (int t0 = 0; t0 < S_; t0 += 64) {
        const int buf = (t0 >> 6) & 1;
        const int tn = (t0 + 64) & (S_ - 1);  // prefetch target (wraps harmlessly)
        // ---- QK: rows rg*64..+63, cols t0+tc*16..+15; Q from padded LDS ----
        f32x4 acc[4] = {};
#pragma unroll
        for (int kc = 0; kc < 8; ++kc) {
            short8 qa[4];
#pragma unroll
            for (int fm = 0; fm < 4; ++fm)
                qa[fm] = *(const short8*)((const char*)Qs + (rg * 64 + fm * 16 + l15) * 272 + kc * 64 + quad * 16);
#pragma unroll
            for (int fm = 0; fm < 4; ++fm)
                acc[fm] = __builtin_amdgcn_mfma_f32_16x16x32_bf16(qa[fm], kb[kc], acc[fm], 0, 0, 0);
        }
        // ---- prefetch kb(t+1), Li(t+1): 8 outstanding, covered by exp+barrier ----
#pragma unroll
        for (int kc = 0; kc < 8; ++kc)
            kb[kc] = *(const short8*)(KtBase + (size_t)tn * (D_ * 2) + kc * 64);
        float Li_n = Lc[tn + tc * 16 + l15];
        // ---- P = exp(exp(sc)*invL) -> Ps[buf] ----
        unsigned short* Pw = Ps + buf * 10240 + (tc >> 1) * 5120 + (tc & 1) * 16 + l15;
#pragma unroll
        for (int fm = 0; fm < 4; ++fm)
#pragma unroll
            for (int r = 0; r < 4; ++r) {
                float e = __expf(__expf(acc[fm][r] * INV_SQRT_E) * Li);
                rsacc[fm][r] += e;
                int row = rg * 64 + fm * 16 + quad * 4 + r;
                Pw[row * 40] = f2bf(e);
            }
        __syncthreads();
        // ---- PV: rows rg*64..+63, d-cols dc*64..+63; vb preloaded last iter ----
#pragma unroll
        for (int kk = 0; kk < 2; ++kk) {
            short8 pa[4];
#pragma unroll
            for (int fm = 0; fm < 4; ++fm)
                pa[fm] = *(const short8*)&Ps[buf * 10240 + kk * 5120 + (rg * 64 + fm * 16 + l15) * 40 + quad * 8];
#pragma unroll
            for (int fm = 0; fm < 4; ++fm)
#pragma unroll
                for (int fn = 0; fn < 4; ++fn)
                    zacc[fm][fn] = __builtin_amdgcn_mfma_f32_16x16x32_bf16(pa[fm], vb[kk * 4 + fn], zacc[fm][fn], 0, 0, 0);
        }
        // ---- prefetch vb(t+1): covered by next QK+exp+barrier ----
#pragma unroll
        for (int kk = 0; kk < 2; ++kk)
#pragma unroll
            for (int fn = 0; fn < 4; ++fn)
                vb[kk * 4 + fn] = *(const short8*)(VwBase + ((size_t)(fn * 16) * S_ + tn + kk * 32) * 2);
        Li = Li_n;
    }
    // ---- rowsum reduce ----
#pragma unroll
    for (int fm = 0; fm < 4; ++fm)
#pragma unroll
        for (int r = 0; r < 4; ++r) {
            float v = rsacc[fm][r];
            v += __shfl_xor(v, 1); v += __shfl_xor(v, 2);
            v += __shfl_xor(v, 4); v += __shfl_xor(v, 8);
            if (l15 == 0) atomicAdd(&rsum[rg * 64 + fm * 16 + quad * 4 + r], v);
        }
    __syncthreads();
#pragma unroll
    for (int fm = 0; fm < 4; ++fm)
#pragma unroll
        for (int r = 0; r < 4; ++r) {
            int row = rg * 64 + fm * 16 + quad * 4 + r;
            float inv = 1.0f / rsum[row];
#pragma unroll
            for (int fn = 0; fn < 4; ++fn)
                Zall[(size_t)(bb * S_ + s0 + row) * HD_ + hh * D_ + dc * 64 + fn * 16 + l15] =
                    f2bf(zacc[fm][fn][r] * inv);
        }
}

extern "C" void kernel_launch(void* const* d_in, const int* in_sizes, int n_in,
                              void* d_out, int out_size, void* d_ws, size_t ws_size,
                              hipStream_t stream) {
    const float* Ain = (const float*)d_in[0];
    const float* WQ = (const float*)d_in[1];
    const float* bQ = (const float*)d_in[2];
    const float* WK = (const float*)d_in[3];
    const float* bK = (const float*)d_in[4];
    const float* WV = (const float*)d_in[5];
    const float* bV = (const float*)d_in[6];
    const float* WZ = (const float*)d_in[7];
    const float* bZ = (const float*)d_in[8];
    float* out = (float*)d_out;

    char* ws = (char*)d_ws;
    size_t off = 0;
    auto alloc = [&](size_t bytes) {
        char* p = ws + off;
        off += (bytes + 255) & ~(size_t)255;
        return p;
    };
    unsigned short* Abf = (unsigned short*)alloc((size_t)BS_ * E_ * 2);
    unsigned short* Wqt = (unsigned short*)alloc((size_t)H_ * D_ * E_ * 2);
    unsigned short* Wkt = (unsigned short*)alloc((size_t)H_ * D_ * E_ * 2);
    unsigned short* Wvt = (unsigned short*)alloc((size_t)H_ * D_ * E_ * 2);
    unsigned short* Wzt = (unsigned short*)alloc((size_t)E_ * HD_ * 2);
    unsigned short* Qb = (unsigned short*)alloc((size_t)BH_ * S_ * D_ * 2);
    unsigned short* Kb = (unsigned short*)alloc((size_t)BH_ * S_ * D_ * 2);
    unsigned short* Vb = (unsigned short*)alloc((size_t)BH_ * S_ * D_ * 2);
    unsigned short* Vtb = (unsigned short*)alloc((size_t)BH_ * S_ * D_ * 2);
    unsigned short* Zb = (unsigned short*)alloc((size_t)BS_ * HD_ * 2);
    float* Lc = (float*)alloc((size_t)BH_ * S_ * 4);

    dim3 tb(32, 8);
    cast_k<<<(BS_ * E_ / 4 + 255) / 256, 256, 0, stream>>>(Ain, Abf, BS_ * E_ / 4);
    tcast_k<<<dim3(D_ / 32, E_ / 32, H_), tb, 0, stream>>>(WQ, Wqt, E_, D_);
    tcast_k<<<dim3(D_ / 32, E_ / 32, H_), tb, 0, stream>>>(WK, Wkt, E_, D_);
    tcast_k<<<dim3(D_ / 32, E_ / 32, H_), tb, 0, stream>>>(WV, Wvt, E_, D_);
    tcast_k<<<dim3(E_ / 32, HD_ / 32, 1), tb, 0, stream>>>(WZ, Wzt, HD_, E_);

    gemm_qkv_k<<<dim3(HD_ / 128, BS_ / 128), 256, 0, stream>>>(Abf, Wqt, bQ, Qb);
    gemm_qkv_k<<<dim3(HD_ / 128, BS_ / 128), 256, 0, stream>>>(Abf, Wkt, bK, Kb);
    gemm_qkv_k<<<dim3(HD_ / 128, BS_ / 128), 256, 0, stream>>>(Abf, Wvt, bV, Vb);

    tbf_k<<<dim3(D_ / 32, S_ / 32, BH_), tb, 0, stream>>>(Vb, Vtb);

    colsum_k<<<dim3(BH_ * S_ / 128), 512, 0, stream>>>(Qb, Kb, Lc);
    flash10_k<<<dim3(BH_ * S_ / 128), 512, 0, stream>>>(Qb, Kb, Vtb, Lc, Zb);

    gemm_out_k<<<dim3(E_ / 128, BS_ / 128), 256, 0, stream>>>(Zb, Wzt, bZ, out);
}

// Round 6
// 723.726 us; speedup vs baseline: 1.1237x; 1.0000x over previous
//
#include <hip/hip_runtime.h>

typedef __attribute__((ext_vector_type(8))) short short8;
typedef __attribute__((ext_vector_type(4))) float f32x4;

constexpr int B_ = 4, S_ = 2048, E_ = 1024, H_ = 8, D_ = 256;
constexpr int HD_ = H_ * D_;   // 2048
constexpr int BS_ = B_ * S_;   // 8192
constexpr int BH_ = B_ * H_;   // 32
constexpr float INV_SQRT_E = 0.03125f;  // 1/sqrt(1024)

__device__ __forceinline__ unsigned short f2bf(float f) {
    union { float f; unsigned u; } x; x.f = f;
    unsigned r = (x.u + 0x7fffu + ((x.u >> 16) & 1u)) >> 16;
    return (unsigned short)r;
}

__device__ __forceinline__ void gl_lds16(const void* g, void* lds) {
    __builtin_amdgcn_global_load_lds((const __attribute__((address_space(1))) void*)g,
                                     (__attribute__((address_space(3))) void*)lds, 16, 0, 0);
}

// ---------------- cast A fp32 -> bf16 (vectorized) ----------------
__global__ __launch_bounds__(256) void cast_k(const float* __restrict__ src,
                                              unsigned short* __restrict__ dst, int n4) {
    int i = blockIdx.x * 256 + threadIdx.x;
    if (i >= n4) return;
    float4 v = reinterpret_cast<const float4*>(src)[i];
    ushort4 o;
    o.x = f2bf(v.x); o.y = f2bf(v.y); o.z = f2bf(v.z); o.w = f2bf(v.w);
    reinterpret_cast<ushort4*>(dst)[i] = o;
}

// ------------- batched transpose+cast: (bt,R,C) f32 -> (bt,C,R) bf16 -------------
__global__ __launch_bounds__(256) void tcast_k(const float* __restrict__ src,
                                               unsigned short* __restrict__ dst, int R, int C) {
    __shared__ float tile[32][33];
    int b = blockIdx.z;
    const float* s = src + (size_t)b * R * C;
    unsigned short* d = dst + (size_t)b * R * C;
    int c0 = blockIdx.x * 32, r0 = blockIdx.y * 32;
    int tx = threadIdx.x, ty = threadIdx.y;
#pragma unroll
    for (int i = 0; i < 4; ++i)
        tile[ty + i * 8][tx] = s[(size_t)(r0 + ty + i * 8) * C + c0 + tx];
    __syncthreads();
#pragma unroll
    for (int i = 0; i < 4; ++i)
        d[(size_t)(c0 + ty + i * 8) * R + r0 + tx] = f2bf(tile[tx][ty + i * 8]);
}

// ------------- bf16 transpose: (BH,S,D) -> (BH,D,S) -------------
__global__ __launch_bounds__(256) void tbf_k(const unsigned short* __restrict__ src,
                                             unsigned short* __restrict__ dst) {
    __shared__ unsigned short tile[32][33];
    int bh = blockIdx.z;
    int d0 = blockIdx.x * 32, s0 = blockIdx.y * 32;
    int tx = threadIdx.x, ty = threadIdx.y;
#pragma unroll
    for (int i = 0; i < 4; ++i)
        tile[ty + i * 8][tx] = src[((size_t)bh * S_ + s0 + ty + i * 8) * D_ + d0 + tx];
    __syncthreads();
#pragma unroll
    for (int i = 0; i < 4; ++i)
        dst[((size_t)bh * D_ + d0 + ty + i * 8) * S_ + s0 + tx] = tile[tx][ty + i * 8];
}

// ------------- QKV GEMM: A(BS,E) x Wt(n)[k] -> relu(+bias) -> (B,H,S,D) bf16 -------------
__global__ __launch_bounds__(256) void gemm_qkv_k(const unsigned short* __restrict__ A,
                                                  const unsigned short* __restrict__ Bt,
                                                  const float* __restrict__ bias,
                                                  unsigned short* __restrict__ out) {
    __shared__ __align__(16) unsigned short As[128 * 32];
    __shared__ __align__(16) unsigned short Bs[128 * 32];
    const int tid = threadIdx.x;
    const int wave = tid >> 6, lane = tid & 63;
    const int quad = lane >> 4, l15 = lane & 15;
    const int wm = wave >> 1, wn = wave & 1;
    const int m0 = blockIdx.y * 128, n0 = blockIdx.x * 128;
    const int c1 = tid, c2 = tid + 256;
    const int r1 = c1 >> 2, kc1 = (c1 & 3) * 8;
    const int r2 = c2 >> 2, kc2 = (c2 & 3) * 8;
    char* aB1 = (char*)As + wave * 1024; char* aB2 = aB1 + 4096;
    char* bB1 = (char*)Bs + wave * 1024; char* bB2 = bB1 + 4096;
    const unsigned short* a1 = A + (size_t)(m0 + r1) * E_ + kc1;
    const unsigned short* a2 = A + (size_t)(m0 + r2) * E_ + kc2;
    const unsigned short* b1 = Bt + (size_t)(n0 + r1) * E_ + kc1;
    const unsigned short* b2 = Bt + (size_t)(n0 + r2) * E_ + kc2;
    f32x4 acc[4][4] = {};
    for (int k0 = 0; k0 < E_; k0 += 32) {
        __syncthreads();
        gl_lds16(a1 + k0, aB1);
        gl_lds16(a2 + k0, aB2);
        gl_lds16(b1 + k0, bB1);
        gl_lds16(b2 + k0, bB2);
        __syncthreads();
        short8 af[4], bf[4];
        const short* Ass = (const short*)As;
        const short* Bss = (const short*)Bs;
#pragma unroll
        for (int f = 0; f < 4; ++f) {
            af[f] = *(const short8*)&Ass[(wm * 64 + f * 16 + l15) * 32 + quad * 8];
            bf[f] = *(const short8*)&Bss[(wn * 64 + f * 16 + l15) * 32 + quad * 8];
        }
#pragma unroll
        for (int fm = 0; fm < 4; ++fm)
#pragma unroll
            for (int fn = 0; fn < 4; ++fn)
                acc[fm][fn] = __builtin_amdgcn_mfma_f32_16x16x32_bf16(af[fm], bf[fn], acc[fm][fn], 0, 0, 0);
    }
#pragma unroll
    for (int fm = 0; fm < 4; ++fm) {
        int mbase = m0 + wm * 64 + fm * 16 + quad * 4;
#pragma unroll
        for (int fn = 0; fn < 4; ++fn) {
            int n = n0 + wn * 64 + fn * 16 + l15;
            int h = n >> 8, d = n & 255;
            float bv = bias[n];
#pragma unroll
            for (int r = 0; r < 4; ++r) {
                int m = mbase + r;
                int b = m >> 11, s = m & 2047;
                float v = fmaxf(acc[fm][fn][r] + bv, 0.0f);
                out[((size_t)(b * H_ + h) * S_ + s) * D_ + d] = f2bf(v);
            }
        }
    }
}

// ------------- output GEMM: Zall(BS,HD) x Wzt(n)[k] + bZ -> fp32 (BS,E) -------------
__global__ __launch_bounds__(256) void gemm_out_k(const unsigned short* __restrict__ A,
                                                  const unsigned short* __restrict__ Bt,
                                                  const float* __restrict__ bias,
                                                  float* __restrict__ out) {
    __shared__ __align__(16) unsigned short As[128 * 32];
    __shared__ __align__(16) unsigned short Bs[128 * 32];
    const int tid = threadIdx.x;
    const int wave = tid >> 6, lane = tid & 63;
    const int quad = lane >> 4, l15 = lane & 15;
    const int wm = wave >> 1, wn = wave & 1;
    const int m0 = blockIdx.y * 128, n0 = blockIdx.x * 128;
    const int c1 = tid, c2 = tid + 256;
    const int r1 = c1 >> 2, kc1 = (c1 & 3) * 8;
    const int r2 = c2 >> 2, kc2 = (c2 & 3) * 8;
    char* aB1 = (char*)As + wave * 1024; char* aB2 = aB1 + 4096;
    char* bB1 = (char*)Bs + wave * 1024; char* bB2 = bB1 + 4096;
    const unsigned short* a1 = A + (size_t)(m0 + r1) * HD_ + kc1;
    const unsigned short* a2 = A + (size_t)(m0 + r2) * HD_ + kc2;
    const unsigned short* b1 = Bt + (size_t)(n0 + r1) * HD_ + kc1;
    const unsigned short* b2 = Bt + (size_t)(n0 + r2) * HD_ + kc2;
    f32x4 acc[4][4] = {};
    for (int k0 = 0; k0 < HD_; k0 += 32) {
        __syncthreads();
        gl_lds16(a1 + k0, aB1);
        gl_lds16(a2 + k0, aB2);
        gl_lds16(b1 + k0, bB1);
        gl_lds16(b2 + k0, bB2);
        __syncthreads();
        short8 af[4], bf[4];
        const short* Ass = (const short*)As;
        const short* Bss = (const short*)Bs;
#pragma unroll
        for (int f = 0; f < 4; ++f) {
            af[f] = *(const short8*)&Ass[(wm * 64 + f * 16 + l15) * 32 + quad * 8];
            bf[f] = *(const short8*)&Bss[(wn * 64 + f * 16 + l15) * 32 + quad * 8];
        }
#pragma unroll
        for (int fm = 0; fm < 4; ++fm)
#pragma unroll
            for (int fn = 0; fn < 4; ++fn)
                acc[fm][fn] = __builtin_amdgcn_mfma_f32_16x16x32_bf16(af[fm], bf[fn], acc[fm][fn], 0, 0, 0);
    }
#pragma unroll
    for (int fm = 0; fm < 4; ++fm) {
        int mbase = m0 + wm * 64 + fm * 16 + quad * 4;
#pragma unroll
        for (int fn = 0; fn < 4; ++fn) {
            int n = n0 + wn * 64 + fn * 16 + l15;
            float bv = bias[n];
#pragma unroll
            for (int r = 0; r < 4; ++r)
                out[(size_t)(mbase + r) * E_ + n] = acc[fm][fn][r] + bv;
        }
    }
}

// ======== colsum_k v4: TBLK=128, XCD-affine. K-frags in regs, qf prefetch,
// zero LDS in s-loop. (unchanged from r5) ========
__global__ __launch_bounds__(512, 2) void colsum_k(const unsigned short* __restrict__ Q,
                                                   const unsigned short* __restrict__ K,
                                                   float* __restrict__ invLcol) {
    __shared__ float part[8][64];
    const int tid = threadIdx.x;
    const int wave = tid >> 6, lane = tid & 63;
    const int quad = lane >> 4, l15 = lane & 15;
    const int tg = wave >> 2, sg = wave & 3;
    const int p = blockIdx.x;
    const int bh = (p & 7) + 8 * ((p >> 3) >> 4);   // head locked to XCD p%8
    const int t0 = ((p >> 3) & 15) * 128;
    const unsigned short* Qh = Q + (size_t)bh * S_ * D_;
    const unsigned short* Kh = K + (size_t)bh * S_ * D_;
    short8 kf[32];
#pragma unroll
    for (int kc = 0; kc < 8; ++kc)
#pragma unroll
        for (int fm = 0; fm < 4; ++fm)
            kf[kc * 4 + fm] = *(const short8*)&Kh[(size_t)(t0 + tg * 64 + fm * 16 + l15) * D_ + kc * 32 + quad * 8];
    float rl[4][4] = {};
    const unsigned short* Qw = Qh + (size_t)(sg * 16 + l15) * D_ + quad * 8;
    short8 qf[8];
#pragma unroll
    for (int kc = 0; kc < 8; ++kc) qf[kc] = *(const short8*)&Qw[kc * 32];
    for (int s0 = 0; s0 < S_; s0 += 64) {
        f32x4 acc[4] = {};
#pragma unroll
        for (int kc = 0; kc < 8; ++kc)
#pragma unroll
            for (int fm = 0; fm < 4; ++fm)
                acc[fm] = __builtin_amdgcn_mfma_f32_16x16x32_bf16(kf[kc * 4 + fm], qf[kc], acc[fm], 0, 0, 0);
        int sn = (s0 + 64) & (S_ - 1);
#pragma unroll
        for (int kc = 0; kc < 8; ++kc)
            qf[kc] = *(const short8*)&Qw[(size_t)sn * D_ + kc * 32];
#pragma unroll
        for (int fm = 0; fm < 4; ++fm)
#pragma unroll
            for (int r = 0; r < 4; ++r)
                rl[fm][r] += __expf(acc[fm][r] * INV_SQRT_E);
    }
#pragma unroll
    for (int fm = 0; fm < 4; ++fm)
#pragma unroll
        for (int r = 0; r < 4; ++r) {
            float v = rl[fm][r];
            v += __shfl_xor(v, 1); v += __shfl_xor(v, 2);
            v += __shfl_xor(v, 4); v += __shfl_xor(v, 8);
            if (l15 == 0) part[wave][fm * 16 + quad * 4 + r] = v;
        }
    __syncthreads();
    if (tid < 128) {
        int tg2 = tid >> 6, i = tid & 63;
        float s = part[tg2 * 4 + 0][i] + part[tg2 * 4 + 1][i] +
                  part[tg2 * 4 + 2][i] + part[tg2 * 4 + 3][i];
        invLcol[(size_t)bh * S_ + t0 + tid] = 1.0f / s;
    }
}

// ======== flash11_k: LDS-pipe diet. Diagnosis (r5): LDS-throughput-bound
// (flash8 FETCH 288MB == flash10 49MB == 273us; conflicts 2.176e7 identical
// across different Qs layouts => ALL from Ps stride-40).
// Fix 1: TBLK=128 -> each Qs fragment feeds 2 K-frags (8 MFMA/kc) => Qs reads
//   per unit work halve (256 vs 512 b128 per 128-t).
// Fix 2: Ps stride 132 shorts (264B = 66dw = 2 mod 32): b16 writes hit banks
//   quad*8+(l15>>1) = all 32, 2 lanes/bank (free); b128 reads start 2*l15+4*quad
//   = balanced 8 touches/bank. Single Ps buffer, 2 barriers/tile (same rate).
// kb flat rolling-8 over (kc,kbi), 4-kc L2 lookahead; vb rolling kk-pairs.
// LDS 67.5KB -> 2 blocks/CU. Regs ~215 (zacc64+acc32+kb32+vb32+rsacc16+misc). ========
__global__ __launch_bounds__(512, 2) void flash11_k(const unsigned short* __restrict__ Q,
                                                    const unsigned short* __restrict__ K,
                                                    const unsigned short* __restrict__ Vt,
                                                    const float* __restrict__ invLcol,
                                                    unsigned short* __restrict__ Zall) {
    __shared__ __align__(16) unsigned short Qs[128 * 136];  // stride 272B (proven clean)
    __shared__ __align__(16) unsigned short Ps[128 * 132];  // stride 264B (derived clean)
    __shared__ float rsum[128];
    const int tid = threadIdx.x;
    const int wave = tid >> 6, lane = tid & 63;
    const int quad = lane >> 4, l15 = lane & 15;
    const int rg = wave >> 2, tc = wave & 3;  // QK: row-group of 64, t-cols of 32
    const int dc = wave & 3;                  // PV: d-cols of 64
    const int p = blockIdx.x;
    const int bh = (p & 7) + 8 * ((p >> 3) >> 4);   // head locked to XCD p%8
    const int s0 = ((p >> 3) & 15) * 128;
    const int bb = bh >> 3, hh = bh & 7;
    const unsigned short* Qh = Q + (size_t)bh * S_ * D_;
    const unsigned short* Kh = K + (size_t)bh * S_ * D_;
    const unsigned short* Vh = Vt + (size_t)bh * D_ * S_;
    const float* Lc = invLcol + (size_t)bh * S_;

    // ---- stage Q -> Qs (padded rows) ----
    {
        int row = tid >> 2, cb = (tid & 3) * 128;
        const char* src = (const char*)(Qh + (size_t)(s0 + row) * D_) + cb;
        char* dst = (char*)Qs + row * 272 + cb;
#pragma unroll
        for (int i = 0; i < 8; ++i)
            *(short8*)(dst + i * 16) = *(const short8*)(src + i * 16);
    }
    if (tid < 128) rsum[tid] = 0.f;
    f32x4 zacc[4][4] = {};
    float rsacc[4][4] = {};

    // kb flat index f in [0,16): t-col = tbase + tc*32 + (f&1)*16 + l15, kc = f>>1
    const unsigned short* KtW = Kh + (size_t)(tc * 32 + l15) * D_ + quad * 8;
    const unsigned short* VwBase = Vh + (size_t)(dc * 64 + l15) * S_ + quad * 8;
    short8 kb[8], vb[8];
#pragma unroll
    for (int f = 0; f < 8; ++f)
        kb[f] = *(const short8*)&KtW[(size_t)((f & 1) * 16) * D_ + (f >> 1) * 32];
#pragma unroll
    for (int kk = 0; kk < 2; ++kk)
#pragma unroll
        for (int fn = 0; fn < 4; ++fn)
            vb[kk * 4 + fn] = *(const short8*)&VwBase[(size_t)(fn * 16) * S_ + kk * 32];
    float Li0 = Lc[tc * 32 + l15];
    float Li1 = Lc[tc * 32 + 16 + l15];
    __syncthreads();  // Qs ready

    for (int t0 = 0; t0 < S_; t0 += 128) {
        const int tn = (t0 + 128) & (S_ - 1);  // wraps harmlessly on last iter
        // ---- QK: rows rg*64..+63, cols t0+tc*32..+31 ----
        f32x4 acc[4][2] = {};
#pragma unroll
        for (int kc = 0; kc < 8; ++kc) {
            short8 qa[4];
#pragma unroll
            for (int fm = 0; fm < 4; ++fm)
                qa[fm] = *(const short8*)((const char*)Qs + (rg * 64 + fm * 16 + l15) * 272 + kc * 64 + quad * 16);
            short8 k0 = kb[(2 * kc) & 7], k1 = kb[(2 * kc + 1) & 7];
            // rolling prefetch: flat f+8 (4 kc ahead; crosses into next tile)
            if (kc < 4) {
                kb[(2 * kc) & 7]     = *(const short8*)&KtW[(size_t)(t0 + 0)  * D_ + (size_t)(kc + 4) * 32];
                kb[(2 * kc + 1) & 7] = *(const short8*)&KtW[(size_t)(t0 + 16) * D_ + (size_t)(kc + 4) * 32];
            } else {
                kb[(2 * kc) & 7]     = *(const short8*)&KtW[(size_t)(tn + 0)  * D_ + (size_t)(kc - 4) * 32];
                kb[(2 * kc + 1) & 7] = *(const short8*)&KtW[(size_t)(tn + 16) * D_ + (size_t)(kc - 4) * 32];
            }
#pragma unroll
            for (int fm = 0; fm < 4; ++fm) {
                acc[fm][0] = __builtin_amdgcn_mfma_f32_16x16x32_bf16(qa[fm], k0, acc[fm][0], 0, 0, 0);
                acc[fm][1] = __builtin_amdgcn_mfma_f32_16x16x32_bf16(qa[fm], k1, acc[fm][1], 0, 0, 0);
            }
        }
        float Li0n = Lc[tn + tc * 32 + l15];
        float Li1n = Lc[tn + tc * 32 + 16 + l15];
        // ---- P = exp(exp(sc)*invL) -> Ps (stride 132) ----
#pragma unroll
        for (int fm = 0; fm < 4; ++fm)
#pragma unroll
            for (int r = 0; r < 4; ++r) {
                int row = rg * 64 + fm * 16 + quad * 4 + r;
                float e0 = __expf(__expf(acc[fm][0][r] * INV_SQRT_E) * Li0);
                float e1 = __expf(__expf(acc[fm][1][r] * INV_SQRT_E) * Li1);
                rsacc[fm][r] += e0 + e1;
                Ps[row * 132 + tc * 32 + l15] = f2bf(e0);
                Ps[row * 132 + tc * 32 + 16 + l15] = f2bf(e1);
            }
        __syncthreads();  // Ps ready
        // ---- PV kk=0,1 (vb preloaded) ----
#pragma unroll
        for (int kk = 0; kk < 2; ++kk) {
            short8 pa[4];
#pragma unroll
            for (int fm = 0; fm < 4; ++fm)
                pa[fm] = *(const short8*)&Ps[(rg * 64 + fm * 16 + l15) * 132 + kk * 32 + quad * 8];
#pragma unroll
            for (int fm = 0; fm < 4; ++fm)
#pragma unroll
                for (int fn = 0; fn < 4; ++fn)
                    zacc[fm][fn] = __builtin_amdgcn_mfma_f32_16x16x32_bf16(pa[fm], vb[kk * 4 + fn], zacc[fm][fn], 0, 0, 0);
        }
        // ---- load vb kk=2,3 (WAR into same regs) ----
#pragma unroll
        for (int kk = 0; kk < 2; ++kk)
#pragma unroll
            for (int fn = 0; fn < 4; ++fn)
                vb[kk * 4 + fn] = *(const short8*)&VwBase[(size_t)(fn * 16) * S_ + t0 + (kk + 2) * 32];
        // ---- PV kk=2,3 ----
#pragma unroll
        for (int kk = 0; kk < 2; ++kk) {
            short8 pa[4];
#pragma unroll
            for (int fm = 0; fm < 4; ++fm)
                pa[fm] = *(const short8*)&Ps[(rg * 64 + fm * 16 + l15) * 132 + (kk + 2) * 32 + quad * 8];
#pragma unroll
            for (int fm = 0; fm < 4; ++fm)
#pragma unroll
                for (int fn = 0; fn < 4; ++fn)
                    zacc[fm][fn] = __builtin_amdgcn_mfma_f32_16x16x32_bf16(pa[fm], vb[kk * 4 + fn], zacc[fm][fn], 0, 0, 0);
        }
        // ---- prefetch next-tile vb kk=0,1 ----
#pragma unroll
        for (int kk = 0; kk < 2; ++kk)
#pragma unroll
            for (int fn = 0; fn < 4; ++fn)
                vb[kk * 4 + fn] = *(const short8*)&VwBase[(size_t)(fn * 16) * S_ + tn + kk * 32];
        __syncthreads();  // PV done reading Ps; next tile may overwrite
        Li0 = Li0n; Li1 = Li1n;
    }
    // ---- rowsum reduce: wave (rg,tc) holds partials for its 32 t-cols ----
#pragma unroll
    for (int fm = 0; fm < 4; ++fm)
#pragma unroll
        for (int r = 0; r < 4; ++r) {
            float v = rsacc[fm][r];
            v += __shfl_xor(v, 1); v += __shfl_xor(v, 2);
            v += __shfl_xor(v, 4); v += __shfl_xor(v, 8);
            if (l15 == 0) atomicAdd(&rsum[rg * 64 + fm * 16 + quad * 4 + r], v);
        }
    __syncthreads();
#pragma unroll
    for (int fm = 0; fm < 4; ++fm)
#pragma unroll
        for (int r = 0; r < 4; ++r) {
            int row = rg * 64 + fm * 16 + quad * 4 + r;
            float inv = 1.0f / rsum[row];
#pragma unroll
            for (int fn = 0; fn < 4; ++fn)
                Zall[(size_t)(bb * S_ + s0 + row) * HD_ + hh * D_ + dc * 64 + fn * 16 + l15] =
                    f2bf(zacc[fm][fn][r] * inv);
        }
}

extern "C" void kernel_launch(void* const* d_in, const int* in_sizes, int n_in,
                              void* d_out, int out_size, void* d_ws, size_t ws_size,
                              hipStream_t stream) {
    const float* Ain = (const float*)d_in[0];
    const float* WQ = (const float*)d_in[1];
    const float* bQ = (const float*)d_in[2];
    const float* WK = (const float*)d_in[3];
    const float* bK = (const float*)d_in[4];
    const float* WV = (const float*)d_in[5];
    const float* bV = (const float*)d_in[6];
    const float* WZ = (const float*)d_in[7];
    const float* bZ = (const float*)d_in[8];
    float* out = (float*)d_out;

    char* ws = (char*)d_ws;
    size_t off = 0;
    auto alloc = [&](size_t bytes) {
        char* p = ws + off;
        off += (bytes + 255) & ~(size_t)255;
        return p;
    };
    unsigned short* Abf = (unsigned short*)alloc((size_t)BS_ * E_ * 2);
    unsigned short* Wqt = (unsigned short*)alloc((size_t)H_ * D_ * E_ * 2);
    unsigned short* Wkt = (unsigned short*)alloc((size_t)H_ * D_ * E_ * 2);
    unsigned short* Wvt = (unsigned short*)alloc((size_t)H_ * D_ * E_ * 2);
    unsigned short* Wzt = (unsigned short*)alloc((size_t)E_ * HD_ * 2);
    unsigned short* Qb = (unsigned short*)alloc((size_t)BH_ * S_ * D_ * 2);
    unsigned short* Kb = (unsigned short*)alloc((size_t)BH_ * S_ * D_ * 2);
    unsigned short* Vb = (unsigned short*)alloc((size_t)BH_ * S_ * D_ * 2);
    unsigned short* Vtb = (unsigned short*)alloc((size_t)BH_ * S_ * D_ * 2);
    unsigned short* Zb = (unsigned short*)alloc((size_t)BS_ * HD_ * 2);
    float* Lc = (float*)alloc((size_t)BH_ * S_ * 4);

    dim3 tb(32, 8);
    cast_k<<<(BS_ * E_ / 4 + 255) / 256, 256, 0, stream>>>(Ain, Abf, BS_ * E_ / 4);
    tcast_k<<<dim3(D_ / 32, E_ / 32, H_), tb, 0, stream>>>(WQ, Wqt, E_, D_);
    tcast_k<<<dim3(D_ / 32, E_ / 32, H_), tb, 0, stream>>>(WK, Wkt, E_, D_);
    tcast_k<<<dim3(D_ / 32, E_ / 32, H_), tb, 0, stream>>>(WV, Wvt, E_, D_);
    tcast_k<<<dim3(E_ / 32, HD_ / 32, 1), tb, 0, stream>>>(WZ, Wzt, HD_, E_);

    gemm_qkv_k<<<dim3(HD_ / 128, BS_ / 128), 256, 0, stream>>>(Abf, Wqt, bQ, Qb);
    gemm_qkv_k<<<dim3(HD_ / 128, BS_ / 128), 256, 0, stream>>>(Abf, Wkt, bK, Kb);
    gemm_qkv_k<<<dim3(HD_ / 128, BS_ / 128), 256, 0, stream>>>(Abf, Wvt, bV, Vb);

    tbf_k<<<dim3(D_ / 32, S_ / 32, BH_), tb, 0, stream>>>(Vb, Vtb);

    colsum_k<<<dim3(BH_ * S_ / 128), 512, 0, stream>>>(Qb, Kb, Lc);
    flash11_k<<<dim3(BH_ * S_ / 128), 512, 0, stream>>>(Qb, Kb, Vtb, Lc, Zb);

    gemm_out_k<<<dim3(E_ / 128, BS_ / 128), 256, 0, stream>>>(Zb, Wzt, bZ, out);
}

// Round 7
// 667.856 us; speedup vs baseline: 1.2177x; 1.0837x over previous
//
#include <hip/hip_runtime.h>

typedef __attribute__((ext_vector_type(8))) short short8;
typedef __attribute__((ext_vector_type(4))) float f32x4;

constexpr int B_ = 4, S_ = 2048, E_ = 1024, H_ = 8, D_ = 256;
constexpr int HD_ = H_ * D_;   // 2048
constexpr int BS_ = B_ * S_;   // 8192
constexpr int BH_ = B_ * H_;   // 32
constexpr float INV_SQRT_E = 0.03125f;  // 1/sqrt(1024)

__device__ __forceinline__ unsigned short f2bf(float f) {
    union { float f; unsigned u; } x; x.f = f;
    unsigned r = (x.u + 0x7fffu + ((x.u >> 16) & 1u)) >> 16;
    return (unsigned short)r;
}

__device__ __forceinline__ unsigned pk2(float a, float b) {
    return (unsigned)f2bf(a) | ((unsigned)f2bf(b) << 16);
}

__device__ __forceinline__ void gl_lds16(const void* g, void* lds) {
    __builtin_amdgcn_global_load_lds((const __attribute__((address_space(1))) void*)g,
                                     (__attribute__((address_space(3))) void*)lds, 16, 0, 0);
}

// ---------------- cast A fp32 -> bf16 (vectorized) ----------------
__global__ __launch_bounds__(256) void cast_k(const float* __restrict__ src,
                                              unsigned short* __restrict__ dst, int n4) {
    int i = blockIdx.x * 256 + threadIdx.x;
    if (i >= n4) return;
    float4 v = reinterpret_cast<const float4*>(src)[i];
    ushort4 o;
    o.x = f2bf(v.x); o.y = f2bf(v.y); o.z = f2bf(v.z); o.w = f2bf(v.w);
    reinterpret_cast<ushort4*>(dst)[i] = o;
}

// ------------- batched transpose+cast: (bt,R,C) f32 -> (bt,C,R) bf16 -------------
__global__ __launch_bounds__(256) void tcast_k(const float* __restrict__ src,
                                               unsigned short* __restrict__ dst, int R, int C) {
    __shared__ float tile[32][33];
    int b = blockIdx.z;
    const float* s = src + (size_t)b * R * C;
    unsigned short* d = dst + (size_t)b * R * C;
    int c0 = blockIdx.x * 32, r0 = blockIdx.y * 32;
    int tx = threadIdx.x, ty = threadIdx.y;
#pragma unroll
    for (int i = 0; i < 4; ++i)
        tile[ty + i * 8][tx] = s[(size_t)(r0 + ty + i * 8) * C + c0 + tx];
    __syncthreads();
#pragma unroll
    for (int i = 0; i < 4; ++i)
        d[(size_t)(c0 + ty + i * 8) * R + r0 + tx] = f2bf(tile[tx][ty + i * 8]);
}

// ------------- bf16 transpose: (BH,S,D) -> (BH,D,S) -------------
__global__ __launch_bounds__(256) void tbf_k(const unsigned short* __restrict__ src,
                                             unsigned short* __restrict__ dst) {
    __shared__ unsigned short tile[32][33];
    int bh = blockIdx.z;
    int d0 = blockIdx.x * 32, s0 = blockIdx.y * 32;
    int tx = threadIdx.x, ty = threadIdx.y;
#pragma unroll
    for (int i = 0; i < 4; ++i)
        tile[ty + i * 8][tx] = src[((size_t)bh * S_ + s0 + ty + i * 8) * D_ + d0 + tx];
    __syncthreads();
#pragma unroll
    for (int i = 0; i < 4; ++i)
        dst[((size_t)bh * D_ + d0 + ty + i * 8) * S_ + s0 + tx] = tile[tx][ty + i * 8];
}

// ------------- QKV GEMM: A(BS,E) x Wt(n)[k] -> relu(+bias) -> (B,H,S,D) bf16 -------------
__global__ __launch_bounds__(256) void gemm_qkv_k(const unsigned short* __restrict__ A,
                                                  const unsigned short* __restrict__ Bt,
                                                  const float* __restrict__ bias,
                                                  unsigned short* __restrict__ out) {
    __shared__ __align__(16) unsigned short As[128 * 32];
    __shared__ __align__(16) unsigned short Bs[128 * 32];
    const int tid = threadIdx.x;
    const int wave = tid >> 6, lane = tid & 63;
    const int quad = lane >> 4, l15 = lane & 15;
    const int wm = wave >> 1, wn = wave & 1;
    const int m0 = blockIdx.y * 128, n0 = blockIdx.x * 128;
    const int c1 = tid, c2 = tid + 256;
    const int r1 = c1 >> 2, kc1 = (c1 & 3) * 8;
    const int r2 = c2 >> 2, kc2 = (c2 & 3) * 8;
    char* aB1 = (char*)As + wave * 1024; char* aB2 = aB1 + 4096;
    char* bB1 = (char*)Bs + wave * 1024; char* bB2 = bB1 + 4096;
    const unsigned short* a1 = A + (size_t)(m0 + r1) * E_ + kc1;
    const unsigned short* a2 = A + (size_t)(m0 + r2) * E_ + kc2;
    const unsigned short* b1 = Bt + (size_t)(n0 + r1) * E_ + kc1;
    const unsigned short* b2 = Bt + (size_t)(n0 + r2) * E_ + kc2;
    f32x4 acc[4][4] = {};
    for (int k0 = 0; k0 < E_; k0 += 32) {
        __syncthreads();
        gl_lds16(a1 + k0, aB1);
        gl_lds16(a2 + k0, aB2);
        gl_lds16(b1 + k0, bB1);
        gl_lds16(b2 + k0, bB2);
        __syncthreads();
        short8 af[4], bf[4];
        const short* Ass = (const short*)As;
        const short* Bss = (const short*)Bs;
#pragma unroll
        for (int f = 0; f < 4; ++f) {
            af[f] = *(const short8*)&Ass[(wm * 64 + f * 16 + l15) * 32 + quad * 8];
            bf[f] = *(const short8*)&Bss[(wn * 64 + f * 16 + l15) * 32 + quad * 8];
        }
#pragma unroll
        for (int fm = 0; fm < 4; ++fm)
#pragma unroll
            for (int fn = 0; fn < 4; ++fn)
                acc[fm][fn] = __builtin_amdgcn_mfma_f32_16x16x32_bf16(af[fm], bf[fn], acc[fm][fn], 0, 0, 0);
    }
#pragma unroll
    for (int fm = 0; fm < 4; ++fm) {
        int mbase = m0 + wm * 64 + fm * 16 + quad * 4;
#pragma unroll
        for (int fn = 0; fn < 4; ++fn) {
            int n = n0 + wn * 64 + fn * 16 + l15;
            int h = n >> 8, d = n & 255;
            float bv = bias[n];
#pragma unroll
            for (int r = 0; r < 4; ++r) {
                int m = mbase + r;
                int b = m >> 11, s = m & 2047;
                float v = fmaxf(acc[fm][fn][r] + bv, 0.0f);
                out[((size_t)(b * H_ + h) * S_ + s) * D_ + d] = f2bf(v);
            }
        }
    }
}

// ------------- output GEMM: Zall(BS,HD) x Wzt(n)[k] + bZ -> fp32 (BS,E) -------------
__global__ __launch_bounds__(256) void gemm_out_k(const unsigned short* __restrict__ A,
                                                  const unsigned short* __restrict__ Bt,
                                                  const float* __restrict__ bias,
                                                  float* __restrict__ out) {
    __shared__ __align__(16) unsigned short As[128 * 32];
    __shared__ __align__(16) unsigned short Bs[128 * 32];
    const int tid = threadIdx.x;
    const int wave = tid >> 6, lane = tid & 63;
    const int quad = lane >> 4, l15 = lane & 15;
    const int wm = wave >> 1, wn = wave & 1;
    const int m0 = blockIdx.y * 128, n0 = blockIdx.x * 128;
    const int c1 = tid, c2 = tid + 256;
    const int r1 = c1 >> 2, kc1 = (c1 & 3) * 8;
    const int r2 = c2 >> 2, kc2 = (c2 & 3) * 8;
    char* aB1 = (char*)As + wave * 1024; char* aB2 = aB1 + 4096;
    char* bB1 = (char*)Bs + wave * 1024; char* bB2 = bB1 + 4096;
    const unsigned short* a1 = A + (size_t)(m0 + r1) * HD_ + kc1;
    const unsigned short* a2 = A + (size_t)(m0 + r2) * HD_ + kc2;
    const unsigned short* b1 = Bt + (size_t)(n0 + r1) * HD_ + kc1;
    const unsigned short* b2 = Bt + (size_t)(n0 + r2) * HD_ + kc2;
    f32x4 acc[4][4] = {};
    for (int k0 = 0; k0 < HD_; k0 += 32) {
        __syncthreads();
        gl_lds16(a1 + k0, aB1);
        gl_lds16(a2 + k0, aB2);
        gl_lds16(b1 + k0, bB1);
        gl_lds16(b2 + k0, bB2);
        __syncthreads();
        short8 af[4], bf[4];
        const short* Ass = (const short*)As;
        const short* Bss = (const short*)Bs;
#pragma unroll
        for (int f = 0; f < 4; ++f) {
            af[f] = *(const short8*)&Ass[(wm * 64 + f * 16 + l15) * 32 + quad * 8];
            bf[f] = *(const short8*)&Bss[(wn * 64 + f * 16 + l15) * 32 + quad * 8];
        }
#pragma unroll
        for (int fm = 0; fm < 4; ++fm)
#pragma unroll
            for (int fn = 0; fn < 4; ++fn)
                acc[fm][fn] = __builtin_amdgcn_mfma_f32_16x16x32_bf16(af[fm], bf[fn], acc[fm][fn], 0, 0, 0);
    }
#pragma unroll
    for (int fm = 0; fm < 4; ++fm) {
        int mbase = m0 + wm * 64 + fm * 16 + quad * 4;
#pragma unroll
        for (int fn = 0; fn < 4; ++fn) {
            int n = n0 + wn * 64 + fn * 16 + l15;
            float bv = bias[n];
#pragma unroll
            for (int r = 0; r < 4; ++r)
                out[(size_t)(mbase + r) * E_ + n] = acc[fm][fn][r] + bv;
        }
    }
}

// ======== colsum_k v4: TBLK=128, XCD-affine. K-frags in regs, qf prefetch,
// zero LDS in s-loop. (unchanged) ========
__global__ __launch_bounds__(512, 2) void colsum_k(const unsigned short* __restrict__ Q,
                                                   const unsigned short* __restrict__ K,
                                                   float* __restrict__ invLcol) {
    __shared__ float part[8][64];
    const int tid = threadIdx.x;
    const int wave = tid >> 6, lane = tid & 63;
    const int quad = lane >> 4, l15 = lane & 15;
    const int tg = wave >> 2, sg = wave & 3;
    const int p = blockIdx.x;
    const int bh = (p & 7) + 8 * ((p >> 3) >> 4);   // head locked to XCD p%8
    const int t0 = ((p >> 3) & 15) * 128;
    const unsigned short* Qh = Q + (size_t)bh * S_ * D_;
    const unsigned short* Kh = K + (size_t)bh * S_ * D_;
    short8 kf[32];
#pragma unroll
    for (int kc = 0; kc < 8; ++kc)
#pragma unroll
        for (int fm = 0; fm < 4; ++fm)
            kf[kc * 4 + fm] = *(const short8*)&Kh[(size_t)(t0 + tg * 64 + fm * 16 + l15) * D_ + kc * 32 + quad * 8];
    float rl[4][4] = {};
    const unsigned short* Qw = Qh + (size_t)(sg * 16 + l15) * D_ + quad * 8;
    short8 qf[8];
#pragma unroll
    for (int kc = 0; kc < 8; ++kc) qf[kc] = *(const short8*)&Qw[kc * 32];
    for (int s0 = 0; s0 < S_; s0 += 64) {
        f32x4 acc[4] = {};
#pragma unroll
        for (int kc = 0; kc < 8; ++kc)
#pragma unroll
            for (int fm = 0; fm < 4; ++fm)
                acc[fm] = __builtin_amdgcn_mfma_f32_16x16x32_bf16(kf[kc * 4 + fm], qf[kc], acc[fm], 0, 0, 0);
        int sn = (s0 + 64) & (S_ - 1);
#pragma unroll
        for (int kc = 0; kc < 8; ++kc)
            qf[kc] = *(const short8*)&Qw[(size_t)sn * D_ + kc * 32];
#pragma unroll
        for (int fm = 0; fm < 4; ++fm)
#pragma unroll
            for (int r = 0; r < 4; ++r)
                rl[fm][r] += __expf(acc[fm][r] * INV_SQRT_E);
    }
#pragma unroll
    for (int fm = 0; fm < 4; ++fm)
#pragma unroll
        for (int r = 0; r < 4; ++r) {
            float v = rl[fm][r];
            v += __shfl_xor(v, 1); v += __shfl_xor(v, 2);
            v += __shfl_xor(v, 4); v += __shfl_xor(v, 8);
            if (l15 == 0) part[wave][fm * 16 + quad * 4 + r] = v;
        }
    __syncthreads();
    if (tid < 128) {
        int tg2 = tid >> 6, i = tid & 63;
        float s = part[tg2 * 4 + 0][i] + part[tg2 * 4 + 1][i] +
                  part[tg2 * 4 + 2][i] + part[tg2 * 4 + 3][i];
        invLcol[(size_t)bh * S_ + t0 + tid] = 1.0f / s;
    }
}

// ======== flash12_k: swapped-QK, P fully in registers, ONE barrier per 32-t chunk.
// Diagnosis (r4-r6): flash invariant at 272us across conflicts/traffic/LDS-read
// changes => phase-serialization bound. This kernel removes the structure:
//  - mfma(K,Q): C[col=s,row=t] -> each lane owns P for one q-row => softmax &
//    P->bf16 pack are lane-local; NO Ps LDS, NO QK->PV barrier, NO rsum atomics.
//  - K staged into LDS via gl_lds with PERMUTED per-lane global addresses
//    (row(l15)=8*(l15>>2)+(l15&3), +4 odd subtile) so the two QK accumulator
//    tiles ARE the PV A-fragment after pairwise bf16 packing: zero cross-lane ops.
//  - K/V in fragment-order LDS: reads are lane-linear (base+lane*16) = conflict-free.
//  - 4 waves x 32 q-rows; per chunk: stage(c+1) -> QK(8kc x 4mfma) -> exp/pack ->
//    PV(16dt x 2mfma) -> barrier. Q re-read from L2 per chunk (keeps VGPR low;
//    zacc 128 lives in AGPRs; VGPR ~80 => 2 waves/SIMD safe).
// LDS 64KB (2 blocks/CU). XCD-affine mapping kept (r4-proven). ========
__global__ __launch_bounds__(256, 2) void flash12_k(const unsigned short* __restrict__ Q,
                                                    const unsigned short* __restrict__ K,
                                                    const unsigned short* __restrict__ Vt,
                                                    const float* __restrict__ invLcol,
                                                    unsigned short* __restrict__ Zall) {
    __shared__ __align__(16) char KsB[2 * 16 * 1024];  // [buf][seg=kc*2+sub][lane*16]
    __shared__ __align__(16) char VsB[2 * 16 * 1024];  // [buf][dt][lane*16]
    const int tid = threadIdx.x;
    const int wave = tid >> 6, lane = tid & 63;
    const int q = lane >> 4, l15 = lane & 15;
    const int p = blockIdx.x;
    const int bh = (p & 7) + 8 * ((p >> 3) >> 4);   // head locked to XCD p%8
    const int s0 = ((p >> 3) & 15) * 128;
    const int bb = bh >> 3, hh = bh & 7;
    const unsigned short* Qh = Q + (size_t)bh * S_ * D_;
    const unsigned short* Kh = K + (size_t)bh * S_ * D_;
    const unsigned short* Vh = Vt + (size_t)bh * D_ * S_;
    const float* Lc = invLcol + (size_t)bh * S_;
    const int sbase = s0 + wave * 32;
    // permuted K staging row within a 32-t chunk (sub adds +4)
    const int krow = 8 * (l15 >> 2) + (l15 & 3);

    // per-lane source pointers
    const unsigned short* Qw0 = Qh + (size_t)(sbase + l15) * D_ + q * 8;       // st=0
    const unsigned short* Qw1 = Qw0 + (size_t)16 * D_;                         // st=1

    f32x4 zacc[2][16] = {};   // [st][dt] -> AGPRs
    float rsacc[2] = {0.f, 0.f};

    // ---- prologue: stage chunk 0 into buf 0 ----
#pragma unroll
    for (int i = 0; i < 4; ++i) {
        const int seg = wave * 4 + i;
        const int kc = seg >> 1, sub = seg & 1;
        gl_lds16(Kh + (size_t)(sub * 4 + krow) * D_ + kc * 32 + q * 8, KsB + seg * 1024);
        gl_lds16(Vh + (size_t)(seg * 16 + l15) * S_ + q * 8, VsB + seg * 1024);
    }
    __syncthreads();

    for (int c = 0; c < 64; ++c) {
        const int t0 = c * 32;
        const char* Kcur = KsB + (c & 1) * 16384;
        const char* Vcur = VsB + (c & 1) * 16384;
        // ---- stage chunk c+1 into the other buffer (covered by this chunk's compute) ----
        if (c < 63) {
            const int tn = t0 + 32;
            char* Knxt = KsB + ((c & 1) ^ 1) * 16384;
            char* Vnxt = VsB + ((c & 1) ^ 1) * 16384;
#pragma unroll
            for (int i = 0; i < 4; ++i) {
                const int seg = wave * 4 + i;
                const int kc = seg >> 1, sub = seg & 1;
                gl_lds16(Kh + (size_t)(tn + sub * 4 + krow) * D_ + kc * 32 + q * 8, Knxt + seg * 1024);
                gl_lds16(Vh + (size_t)(seg * 16 + l15) * S_ + tn + q * 8, Vnxt + seg * 1024);
            }
        }
        // ---- QK (swapped): acc[st][sub], C[col=s=l15][row=t: sub0 t0+8q+r, sub1 +4] ----
        f32x4 acc[2][2] = {};
#pragma unroll
        for (int kc = 0; kc < 8; ++kc) {
            short8 kf0 = *(const short8*)(Kcur + (kc * 2 + 0) * 1024 + lane * 16);
            short8 kf1 = *(const short8*)(Kcur + (kc * 2 + 1) * 1024 + lane * 16);
            short8 qf0 = *(const short8*)&Qw0[kc * 32];
            short8 qf1 = *(const short8*)&Qw1[kc * 32];
            acc[0][0] = __builtin_amdgcn_mfma_f32_16x16x32_bf16(kf0, qf0, acc[0][0], 0, 0, 0);
            acc[0][1] = __builtin_amdgcn_mfma_f32_16x16x32_bf16(kf1, qf0, acc[0][1], 0, 0, 0);
            acc[1][0] = __builtin_amdgcn_mfma_f32_16x16x32_bf16(kf0, qf1, acc[1][0], 0, 0, 0);
            acc[1][1] = __builtin_amdgcn_mfma_f32_16x16x32_bf16(kf1, qf1, acc[1][1], 0, 0, 0);
        }
        // ---- P = exp(exp(sc)*invL[t]) , lane-local pack to PV A-fragment ----
        const float4 iv0 = *(const float4*)(Lc + t0 + 8 * q);
        const float4 iv1 = *(const float4*)(Lc + t0 + 8 * q + 4);
        short8 pa[2];
#pragma unroll
        for (int st = 0; st < 2; ++st) {
            const f32x4 a0 = acc[st][0], a1 = acc[st][1];
            float e0 = __expf(__expf(a0[0] * INV_SQRT_E) * iv0.x);
            float e1 = __expf(__expf(a0[1] * INV_SQRT_E) * iv0.y);
            float e2 = __expf(__expf(a0[2] * INV_SQRT_E) * iv0.z);
            float e3 = __expf(__expf(a0[3] * INV_SQRT_E) * iv0.w);
            float e4 = __expf(__expf(a1[0] * INV_SQRT_E) * iv1.x);
            float e5 = __expf(__expf(a1[1] * INV_SQRT_E) * iv1.y);
            float e6 = __expf(__expf(a1[2] * INV_SQRT_E) * iv1.z);
            float e7 = __expf(__expf(a1[3] * INV_SQRT_E) * iv1.w);
            rsacc[st] += ((e0 + e1) + (e2 + e3)) + ((e4 + e5) + (e6 + e7));
            union { short8 v; unsigned u[4]; } P;
            P.u[0] = pk2(e0, e1);  // t = t0+8q+0,1
            P.u[1] = pk2(e2, e3);  // t = t0+8q+2,3
            P.u[2] = pk2(e4, e5);  // t = t0+8q+4,5
            P.u[3] = pk2(e6, e7);  // t = t0+8q+6,7
            pa[st] = P.v;
        }
        // ---- PV: zacc[st][dt] += pa[st] x V[t-chunk][dt*16..+15] ----
#pragma unroll
        for (int dt = 0; dt < 16; ++dt) {
            short8 vb = *(const short8*)(Vcur + dt * 1024 + lane * 16);
            zacc[0][dt] = __builtin_amdgcn_mfma_f32_16x16x32_bf16(pa[0], vb, zacc[0][dt], 0, 0, 0);
            zacc[1][dt] = __builtin_amdgcn_mfma_f32_16x16x32_bf16(pa[1], vb, zacc[1][dt], 0, 0, 0);
        }
        __syncthreads();  // staged chunk c+1 landed; all reads of cur done
    }
    // ---- epilogue: rowsum via shfl (P row is lane-local summed over quads), store ----
#pragma unroll
    for (int st = 0; st < 2; ++st) {
        float rs = rsacc[st];
        rs += __shfl_xor(rs, 16);
        rs += __shfl_xor(rs, 32);  // every lane: total rowsum for s = sbase + st*16 + l15
#pragma unroll
        for (int r = 0; r < 4; ++r) {
            const float inv = 1.0f / __shfl(rs, q * 4 + r);
            const size_t rowoff = (size_t)(bb * S_ + sbase + st * 16 + q * 4 + r) * HD_ + hh * D_;
#pragma unroll
            for (int dt = 0; dt < 16; ++dt)
                Zall[rowoff + dt * 16 + l15] = f2bf(zacc[st][dt][r] * inv);
        }
    }
}

extern "C" void kernel_launch(void* const* d_in, const int* in_sizes, int n_in,
                              void* d_out, int out_size, void* d_ws, size_t ws_size,
                              hipStream_t stream) {
    const float* Ain = (const float*)d_in[0];
    const float* WQ = (const float*)d_in[1];
    const float* bQ = (const float*)d_in[2];
    const float* WK = (const float*)d_in[3];
    const float* bK = (const float*)d_in[4];
    const float* WV = (const float*)d_in[5];
    const float* bV = (const float*)d_in[6];
    const float* WZ = (const float*)d_in[7];
    const float* bZ = (const float*)d_in[8];
    float* out = (float*)d_out;

    char* ws = (char*)d_ws;
    size_t off = 0;
    auto alloc = [&](size_t bytes) {
        char* p = ws + off;
        off += (bytes + 255) & ~(size_t)255;
        return p;
    };
    unsigned short* Abf = (unsigned short*)alloc((size_t)BS_ * E_ * 2);
    unsigned short* Wqt = (unsigned short*)alloc((size_t)H_ * D_ * E_ * 2);
    unsigned short* Wkt = (unsigned short*)alloc((size_t)H_ * D_ * E_ * 2);
    unsigned short* Wvt = (unsigned short*)alloc((size_t)H_ * D_ * E_ * 2);
    unsigned short* Wzt = (unsigned short*)alloc((size_t)E_ * HD_ * 2);
    unsigned short* Qb = (unsigned short*)alloc((size_t)BH_ * S_ * D_ * 2);
    unsigned short* Kb = (unsigned short*)alloc((size_t)BH_ * S_ * D_ * 2);
    unsigned short* Vb = (unsigned short*)alloc((size_t)BH_ * S_ * D_ * 2);
    unsigned short* Vtb = (unsigned short*)alloc((size_t)BH_ * S_ * D_ * 2);
    unsigned short* Zb = (unsigned short*)alloc((size_t)BS_ * HD_ * 2);
    float* Lc = (float*)alloc((size_t)BH_ * S_ * 4);

    dim3 tb(32, 8);
    cast_k<<<(BS_ * E_ / 4 + 255) / 256, 256, 0, stream>>>(Ain, Abf, BS_ * E_ / 4);
    tcast_k<<<dim3(D_ / 32, E_ / 32, H_), tb, 0, stream>>>(WQ, Wqt, E_, D_);
    tcast_k<<<dim3(D_ / 32, E_ / 32, H_), tb, 0, stream>>>(WK, Wkt, E_, D_);
    tcast_k<<<dim3(D_ / 32, E_ / 32, H_), tb, 0, stream>>>(WV, Wvt, E_, D_);
    tcast_k<<<dim3(E_ / 32, HD_ / 32, 1), tb, 0, stream>>>(WZ, Wzt, HD_, E_);

    gemm_qkv_k<<<dim3(HD_ / 128, BS_ / 128), 256, 0, stream>>>(Abf, Wqt, bQ, Qb);
    gemm_qkv_k<<<dim3(HD_ / 128, BS_ / 128), 256, 0, stream>>>(Abf, Wkt, bK, Kb);
    gemm_qkv_k<<<dim3(HD_ / 128, BS_ / 128), 256, 0, stream>>>(Abf, Wvt, bV, Vb);

    tbf_k<<<dim3(D_ / 32, S_ / 32, BH_), tb, 0, stream>>>(Vb, Vtb);

    colsum_k<<<dim3(BH_ * S_ / 128), 512, 0, stream>>>(Qb, Kb, Lc);
    flash12_k<<<dim3(BH_ * S_ / 128), 256, 0, stream>>>(Qb, Kb, Vtb, Lc, Zb);

    gemm_out_k<<<dim3(E_ / 128, BS_ / 128), 256, 0, stream>>>(Zb, Wzt, bZ, out);
}

// Round 8
// 638.387 us; speedup vs baseline: 1.2739x; 1.0462x over previous
//
#include <hip/hip_runtime.h>

typedef __attribute__((ext_vector_type(8))) short short8;
typedef __attribute__((ext_vector_type(4))) float f32x4;

constexpr int B_ = 4, S_ = 2048, E_ = 1024, H_ = 8, D_ = 256;
constexpr int HD_ = H_ * D_;   // 2048
constexpr int BS_ = B_ * S_;   // 8192
constexpr int BH_ = B_ * H_;   // 32
constexpr float INV_SQRT_E = 0.03125f;  // 1/sqrt(1024)

__device__ __forceinline__ unsigned short f2bf(float f) {
    union { float f; unsigned u; } x; x.f = f;
    unsigned r = (x.u + 0x7fffu + ((x.u >> 16) & 1u)) >> 16;
    return (unsigned short)r;
}

__device__ __forceinline__ unsigned pk2(float a, float b) {
    return (unsigned)f2bf(a) | ((unsigned)f2bf(b) << 16);
}

__device__ __forceinline__ void gl_lds16(const void* g, void* lds) {
    __builtin_amdgcn_global_load_lds((const __attribute__((address_space(1))) void*)g,
                                     (__attribute__((address_space(3))) void*)lds, 16, 0, 0);
}

// ---------------- cast A fp32 -> bf16 (vectorized) ----------------
__global__ __launch_bounds__(256) void cast_k(const float* __restrict__ src,
                                              unsigned short* __restrict__ dst, int n4) {
    int i = blockIdx.x * 256 + threadIdx.x;
    if (i >= n4) return;
    float4 v = reinterpret_cast<const float4*>(src)[i];
    ushort4 o;
    o.x = f2bf(v.x); o.y = f2bf(v.y); o.z = f2bf(v.z); o.w = f2bf(v.w);
    reinterpret_cast<ushort4*>(dst)[i] = o;
}

// ------------- batched transpose+cast: (bt,R,C) f32 -> (bt,C,R) bf16 -------------
__global__ __launch_bounds__(256) void tcast_k(const float* __restrict__ src,
                                               unsigned short* __restrict__ dst, int R, int C) {
    __shared__ float tile[32][33];
    int b = blockIdx.z;
    const float* s = src + (size_t)b * R * C;
    unsigned short* d = dst + (size_t)b * R * C;
    int c0 = blockIdx.x * 32, r0 = blockIdx.y * 32;
    int tx = threadIdx.x, ty = threadIdx.y;
#pragma unroll
    for (int i = 0; i < 4; ++i)
        tile[ty + i * 8][tx] = s[(size_t)(r0 + ty + i * 8) * C + c0 + tx];
    __syncthreads();
#pragma unroll
    for (int i = 0; i < 4; ++i)
        d[(size_t)(c0 + ty + i * 8) * R + r0 + tx] = f2bf(tile[tx][ty + i * 8]);
}

// ------------- bf16 transpose: (BH,S,D) -> (BH,D,S) -------------
__global__ __launch_bounds__(256) void tbf_k(const unsigned short* __restrict__ src,
                                             unsigned short* __restrict__ dst) {
    __shared__ unsigned short tile[32][33];
    int bh = blockIdx.z;
    int d0 = blockIdx.x * 32, s0 = blockIdx.y * 32;
    int tx = threadIdx.x, ty = threadIdx.y;
#pragma unroll
    for (int i = 0; i < 4; ++i)
        tile[ty + i * 8][tx] = src[((size_t)bh * S_ + s0 + ty + i * 8) * D_ + d0 + tx];
    __syncthreads();
#pragma unroll
    for (int i = 0; i < 4; ++i)
        dst[((size_t)bh * D_ + d0 + ty + i * 8) * S_ + s0 + tx] = tile[tx][ty + i * 8];
}

// ======== gemm_qkv256_k: 256x256 tile, BK=64, 2-phase single-barrier pipeline.
// 8 waves (2M x 4N), per-wave 128x64 out (acc 8x4 f32x4 = 128 AGPR).
// T2 swizzle m201-style: gl_lds dest LINEAR; global source pre-swizzled
// (chunk = lc ^ lrow within each 8-row/1KB segment); ds_read compensates with
// v = (quad ^ (l15&7)) ^ (kcc<<2) -> banks 2-way aliased = free.
// One __syncthreads per K-step (implicit vmcnt0+lgkmcnt0 drain).
// Grid 256 blocks (1/CU); N-panel locked to XCD via p&7. ========
__global__ __launch_bounds__(512, 2) void gemm_qkv256_k(const unsigned short* __restrict__ A,
                                                        const unsigned short* __restrict__ Bt,
                                                        const float* __restrict__ bias,
                                                        unsigned short* __restrict__ out) {
    __shared__ __align__(16) unsigned short As[2][256 * 64];  // 64 KB
    __shared__ __align__(16) unsigned short Bs[2][256 * 64];  // 64 KB
    const int tid = threadIdx.x;
    const int wave = tid >> 6, lane = tid & 63;
    const int quad = lane >> 4, l15 = lane & 15;
    const int wm = wave >> 2, wn = wave & 3;
    const int lrow = lane >> 3, lc = lane & 7;
    const int p = blockIdx.x;
    const int n0 = (p & 7) * 256;          // XCD-locked B panel
    const int m0 = (p >> 3) * 256;
    // staging source offsets (shorts), chunk pre-swizzled: lc ^ lrow
    int aoff[4], boff[4];
#pragma unroll
    for (int i = 0; i < 4; ++i) {
        int rA = m0 + (wave * 4 + i) * 8 + lrow;
        int rB = n0 + (wave * 4 + i) * 8 + lrow;
        aoff[i] = rA * E_ + (lc ^ lrow) * 8;
        boff[i] = rB * E_ + (lc ^ lrow) * 8;
    }
    f32x4 acc[8][4] = {};
    // prologue: stage k0=0 into buf 0
#pragma unroll
    for (int i = 0; i < 4; ++i) {
        gl_lds16(A + aoff[i], (char*)As + (wave * 4 + i) * 1024);
        gl_lds16(Bt + boff[i], (char*)Bs + (wave * 4 + i) * 1024);
    }
    __syncthreads();
    const int v0 = (quad ^ (l15 & 7)) * 16;  // swizzled chunk byte offset, kcc=0
    const int arow = (wm * 128 + l15) * 128; // byte base of A row (fm adds 16*128)
    const int brow = (wn * 64 + l15) * 128;
    for (int k0 = 0; k0 < E_; k0 += 64) {
        const int cur = (k0 >> 6) & 1;
        // stage next K-tile into other buffer
        if (k0 + 64 < E_) {
            char* An = (char*)As + (cur ^ 1) * 32768;
            char* Bn = (char*)Bs + (cur ^ 1) * 32768;
#pragma unroll
            for (int i = 0; i < 4; ++i) {
                gl_lds16(A + aoff[i] + k0 + 64, An + (wave * 4 + i) * 1024);
                gl_lds16(Bt + boff[i] + k0 + 64, Bn + (wave * 4 + i) * 1024);
            }
        }
        const char* Ac = (const char*)As + cur * 32768;
        const char* Bc = (const char*)Bs + cur * 32768;
#pragma unroll
        for (int kcc = 0; kcc < 2; ++kcc) {
            const int vk = v0 ^ (kcc << 6);
            short8 af[8], bf[4];
#pragma unroll
            for (int fm = 0; fm < 8; ++fm)
                af[fm] = *(const short8*)(Ac + arow + fm * 2048 + vk);
#pragma unroll
            for (int fn = 0; fn < 4; ++fn)
                bf[fn] = *(const short8*)(Bc + brow + fn * 2048 + vk);
#pragma unroll
            for (int fm = 0; fm < 8; ++fm)
#pragma unroll
                for (int fn = 0; fn < 4; ++fn)
                    acc[fm][fn] = __builtin_amdgcn_mfma_f32_16x16x32_bf16(af[fm], bf[fn], acc[fm][fn], 0, 0, 0);
        }
        __syncthreads();
    }
    // epilogue: relu(+bias) -> (B,H,S,D) bf16 scatter
#pragma unroll
    for (int fm = 0; fm < 8; ++fm) {
        int mbase = m0 + wm * 128 + fm * 16 + quad * 4;
#pragma unroll
        for (int fn = 0; fn < 4; ++fn) {
            int n = n0 + wn * 64 + fn * 16 + l15;
            int h = n >> 8, d = n & 255;
            float bv = bias[n];
#pragma unroll
            for (int r = 0; r < 4; ++r) {
                int m = mbase + r;
                int b = m >> 11, s = m & 2047;
                float v = fmaxf(acc[fm][fn][r] + bv, 0.0f);
                out[((size_t)(b * H_ + h) * S_ + s) * D_ + d] = f2bf(v);
            }
        }
    }
}

// ------------- output GEMM: Zall(BS,HD) x Wzt(n)[k] + bZ -> fp32 (BS,E) -------------
__global__ __launch_bounds__(256) void gemm_out_k(const unsigned short* __restrict__ A,
                                                  const unsigned short* __restrict__ Bt,
                                                  const float* __restrict__ bias,
                                                  float* __restrict__ out) {
    __shared__ __align__(16) unsigned short As[128 * 32];
    __shared__ __align__(16) unsigned short Bs[128 * 32];
    const int tid = threadIdx.x;
    const int wave = tid >> 6, lane = tid & 63;
    const int quad = lane >> 4, l15 = lane & 15;
    const int wm = wave >> 1, wn = wave & 1;
    const int m0 = blockIdx.y * 128, n0 = blockIdx.x * 128;
    const int c1 = tid, c2 = tid + 256;
    const int r1 = c1 >> 2, kc1 = (c1 & 3) * 8;
    const int r2 = c2 >> 2, kc2 = (c2 & 3) * 8;
    char* aB1 = (char*)As + wave * 1024; char* aB2 = aB1 + 4096;
    char* bB1 = (char*)Bs + wave * 1024; char* bB2 = bB1 + 4096;
    const unsigned short* a1 = A + (size_t)(m0 + r1) * HD_ + kc1;
    const unsigned short* a2 = A + (size_t)(m0 + r2) * HD_ + kc2;
    const unsigned short* b1 = Bt + (size_t)(n0 + r1) * HD_ + kc1;
    const unsigned short* b2 = Bt + (size_t)(n0 + r2) * HD_ + kc2;
    f32x4 acc[4][4] = {};
    for (int k0 = 0; k0 < HD_; k0 += 32) {
        __syncthreads();
        gl_lds16(a1 + k0, aB1);
        gl_lds16(a2 + k0, aB2);
        gl_lds16(b1 + k0, bB1);
        gl_lds16(b2 + k0, bB2);
        __syncthreads();
        short8 af[4], bf[4];
        const short* Ass = (const short*)As;
        const short* Bss = (const short*)Bs;
#pragma unroll
        for (int f = 0; f < 4; ++f) {
            af[f] = *(const short8*)&Ass[(wm * 64 + f * 16 + l15) * 32 + quad * 8];
            bf[f] = *(const short8*)&Bss[(wn * 64 + f * 16 + l15) * 32 + quad * 8];
        }
#pragma unroll
        for (int fm = 0; fm < 4; ++fm)
#pragma unroll
            for (int fn = 0; fn < 4; ++fn)
                acc[fm][fn] = __builtin_amdgcn_mfma_f32_16x16x32_bf16(af[fm], bf[fn], acc[fm][fn], 0, 0, 0);
    }
#pragma unroll
    for (int fm = 0; fm < 4; ++fm) {
        int mbase = m0 + wm * 64 + fm * 16 + quad * 4;
#pragma unroll
        for (int fn = 0; fn < 4; ++fn) {
            int n = n0 + wn * 64 + fn * 16 + l15;
            float bv = bias[n];
#pragma unroll
            for (int r = 0; r < 4; ++r)
                out[(size_t)(mbase + r) * E_ + n] = acc[fm][fn][r] + bv;
        }
    }
}

// ======== colsum_k v4: TBLK=128, XCD-affine. K-frags in regs, qf prefetch,
// zero LDS in s-loop. (unchanged) ========
__global__ __launch_bounds__(512, 2) void colsum_k(const unsigned short* __restrict__ Q,
                                                   const unsigned short* __restrict__ K,
                                                   float* __restrict__ invLcol) {
    __shared__ float part[8][64];
    const int tid = threadIdx.x;
    const int wave = tid >> 6, lane = tid & 63;
    const int quad = lane >> 4, l15 = lane & 15;
    const int tg = wave >> 2, sg = wave & 3;
    const int p = blockIdx.x;
    const int bh = (p & 7) + 8 * ((p >> 3) >> 4);   // head locked to XCD p%8
    const int t0 = ((p >> 3) & 15) * 128;
    const unsigned short* Qh = Q + (size_t)bh * S_ * D_;
    const unsigned short* Kh = K + (size_t)bh * S_ * D_;
    short8 kf[32];
#pragma unroll
    for (int kc = 0; kc < 8; ++kc)
#pragma unroll
        for (int fm = 0; fm < 4; ++fm)
            kf[kc * 4 + fm] = *(const short8*)&Kh[(size_t)(t0 + tg * 64 + fm * 16 + l15) * D_ + kc * 32 + quad * 8];
    float rl[4][4] = {};
    const unsigned short* Qw = Qh + (size_t)(sg * 16 + l15) * D_ + quad * 8;
    short8 qf[8];
#pragma unroll
    for (int kc = 0; kc < 8; ++kc) qf[kc] = *(const short8*)&Qw[kc * 32];
    for (int s0 = 0; s0 < S_; s0 += 64) {
        f32x4 acc[4] = {};
#pragma unroll
        for (int kc = 0; kc < 8; ++kc)
#pragma unroll
            for (int fm = 0; fm < 4; ++fm)
                acc[fm] = __builtin_amdgcn_mfma_f32_16x16x32_bf16(kf[kc * 4 + fm], qf[kc], acc[fm], 0, 0, 0);
        int sn = (s0 + 64) & (S_ - 1);
#pragma unroll
        for (int kc = 0; kc < 8; ++kc)
            qf[kc] = *(const short8*)&Qw[(size_t)sn * D_ + kc * 32];
#pragma unroll
        for (int fm = 0; fm < 4; ++fm)
#pragma unroll
            for (int r = 0; r < 4; ++r)
                rl[fm][r] += __expf(acc[fm][r] * INV_SQRT_E);
    }
#pragma unroll
    for (int fm = 0; fm < 4; ++fm)
#pragma unroll
        for (int r = 0; r < 4; ++r) {
            float v = rl[fm][r];
            v += __shfl_xor(v, 1); v += __shfl_xor(v, 2);
            v += __shfl_xor(v, 4); v += __shfl_xor(v, 8);
            if (l15 == 0) part[wave][fm * 16 + quad * 4 + r] = v;
        }
    __syncthreads();
    if (tid < 128) {
        int tg2 = tid >> 6, i = tid & 63;
        float s = part[tg2 * 4 + 0][i] + part[tg2 * 4 + 1][i] +
                  part[tg2 * 4 + 2][i] + part[tg2 * 4 + 3][i];
        invLcol[(size_t)bh * S_ + t0 + tid] = 1.0f / s;
    }
}

// ======== flash12_k: swapped-QK, P fully in registers, ONE barrier per 32-t chunk.
// (r7-proven: 214us, bank conflicts = 0, correct) ========
__global__ __launch_bounds__(256, 2) void flash12_k(const unsigned short* __restrict__ Q,
                                                    const unsigned short* __restrict__ K,
                                                    const unsigned short* __restrict__ Vt,
                                                    const float* __restrict__ invLcol,
                                                    unsigned short* __restrict__ Zall) {
    __shared__ __align__(16) char KsB[2 * 16 * 1024];  // [buf][seg=kc*2+sub][lane*16]
    __shared__ __align__(16) char VsB[2 * 16 * 1024];  // [buf][dt][lane*16]
    const int tid = threadIdx.x;
    const int wave = tid >> 6, lane = tid & 63;
    const int q = lane >> 4, l15 = lane & 15;
    const int p = blockIdx.x;
    const int bh = (p & 7) + 8 * ((p >> 3) >> 4);   // head locked to XCD p%8
    const int s0 = ((p >> 3) & 15) * 128;
    const int bb = bh >> 3, hh = bh & 7;
    const unsigned short* Qh = Q + (size_t)bh * S_ * D_;
    const unsigned short* Kh = K + (size_t)bh * S_ * D_;
    const unsigned short* Vh = Vt + (size_t)bh * D_ * S_;
    const float* Lc = invLcol + (size_t)bh * S_;
    const int sbase = s0 + wave * 32;
    const int krow = 8 * (l15 >> 2) + (l15 & 3);

    const unsigned short* Qw0 = Qh + (size_t)(sbase + l15) * D_ + q * 8;       // st=0
    const unsigned short* Qw1 = Qw0 + (size_t)16 * D_;                         // st=1

    f32x4 zacc[2][16] = {};   // [st][dt] -> AGPRs
    float rsacc[2] = {0.f, 0.f};

#pragma unroll
    for (int i = 0; i < 4; ++i) {
        const int seg = wave * 4 + i;
        const int kc = seg >> 1, sub = seg & 1;
        gl_lds16(Kh + (size_t)(sub * 4 + krow) * D_ + kc * 32 + q * 8, KsB + seg * 1024);
        gl_lds16(Vh + (size_t)(seg * 16 + l15) * S_ + q * 8, VsB + seg * 1024);
    }
    __syncthreads();

    for (int c = 0; c < 64; ++c) {
        const int t0 = c * 32;
        const char* Kcur = KsB + (c & 1) * 16384;
        const char* Vcur = VsB + (c & 1) * 16384;
        if (c < 63) {
            const int tn = t0 + 32;
            char* Knxt = KsB + ((c & 1) ^ 1) * 16384;
            char* Vnxt = VsB + ((c & 1) ^ 1) * 16384;
#pragma unroll
            for (int i = 0; i < 4; ++i) {
                const int seg = wave * 4 + i;
                const int kc = seg >> 1, sub = seg & 1;
                gl_lds16(Kh + (size_t)(tn + sub * 4 + krow) * D_ + kc * 32 + q * 8, Knxt + seg * 1024);
                gl_lds16(Vh + (size_t)(seg * 16 + l15) * S_ + tn + q * 8, Vnxt + seg * 1024);
            }
        }
        f32x4 acc[2][2] = {};
#pragma unroll
        for (int kc = 0; kc < 8; ++kc) {
            short8 kf0 = *(const short8*)(Kcur + (kc * 2 + 0) * 1024 + lane * 16);
            short8 kf1 = *(const short8*)(Kcur + (kc * 2 + 1) * 1024 + lane * 16);
            short8 qf0 = *(const short8*)&Qw0[kc * 32];
            short8 qf1 = *(const short8*)&Qw1[kc * 32];
            acc[0][0] = __builtin_amdgcn_mfma_f32_16x16x32_bf16(kf0, qf0, acc[0][0], 0, 0, 0);
            acc[0][1] = __builtin_amdgcn_mfma_f32_16x16x32_bf16(kf1, qf0, acc[0][1], 0, 0, 0);
            acc[1][0] = __builtin_amdgcn_mfma_f32_16x16x32_bf16(kf0, qf1, acc[1][0], 0, 0, 0);
            acc[1][1] = __builtin_amdgcn_mfma_f32_16x16x32_bf16(kf1, qf1, acc[1][1], 0, 0, 0);
        }
        const float4 iv0 = *(const float4*)(Lc + t0 + 8 * q);
        const float4 iv1 = *(const float4*)(Lc + t0 + 8 * q + 4);
        short8 pa[2];
#pragma unroll
        for (int st = 0; st < 2; ++st) {
            const f32x4 a0 = acc[st][0], a1 = acc[st][1];
            float e0 = __expf(__expf(a0[0] * INV_SQRT_E) * iv0.x);
            float e1 = __expf(__expf(a0[1] * INV_SQRT_E) * iv0.y);
            float e2 = __expf(__expf(a0[2] * INV_SQRT_E) * iv0.z);
            float e3 = __expf(__expf(a0[3] * INV_SQRT_E) * iv0.w);
            float e4 = __expf(__expf(a1[0] * INV_SQRT_E) * iv1.x);
            float e5 = __expf(__expf(a1[1] * INV_SQRT_E) * iv1.y);
            float e6 = __expf(__expf(a1[2] * INV_SQRT_E) * iv1.z);
            float e7 = __expf(__expf(a1[3] * INV_SQRT_E) * iv1.w);
            rsacc[st] += ((e0 + e1) + (e2 + e3)) + ((e4 + e5) + (e6 + e7));
            union { short8 v; unsigned u[4]; } P;
            P.u[0] = pk2(e0, e1);
            P.u[1] = pk2(e2, e3);
            P.u[2] = pk2(e4, e5);
            P.u[3] = pk2(e6, e7);
            pa[st] = P.v;
        }
#pragma unroll
        for (int dt = 0; dt < 16; ++dt) {
            short8 vb = *(const short8*)(Vcur + dt * 1024 + lane * 16);
            zacc[0][dt] = __builtin_amdgcn_mfma_f32_16x16x32_bf16(pa[0], vb, zacc[0][dt], 0, 0, 0);
            zacc[1][dt] = __builtin_amdgcn_mfma_f32_16x16x32_bf16(pa[1], vb, zacc[1][dt], 0, 0, 0);
        }
        __syncthreads();
    }
#pragma unroll
    for (int st = 0; st < 2; ++st) {
        float rs = rsacc[st];
        rs += __shfl_xor(rs, 16);
        rs += __shfl_xor(rs, 32);
#pragma unroll
        for (int r = 0; r < 4; ++r) {
            const float inv = 1.0f / __shfl(rs, q * 4 + r);
            const size_t rowoff = (size_t)(bb * S_ + sbase + st * 16 + q * 4 + r) * HD_ + hh * D_;
#pragma unroll
            for (int dt = 0; dt < 16; ++dt)
                Zall[rowoff + dt * 16 + l15] = f2bf(zacc[st][dt][r] * inv);
        }
    }
}

extern "C" void kernel_launch(void* const* d_in, const int* in_sizes, int n_in,
                              void* d_out, int out_size, void* d_ws, size_t ws_size,
                              hipStream_t stream) {
    const float* Ain = (const float*)d_in[0];
    const float* WQ = (const float*)d_in[1];
    const float* bQ = (const float*)d_in[2];
    const float* WK = (const float*)d_in[3];
    const float* bK = (const float*)d_in[4];
    const float* WV = (const float*)d_in[5];
    const float* bV = (const float*)d_in[6];
    const float* WZ = (const float*)d_in[7];
    const float* bZ = (const float*)d_in[8];
    float* out = (float*)d_out;

    char* ws = (char*)d_ws;
    size_t off = 0;
    auto alloc = [&](size_t bytes) {
        char* p = ws + off;
        off += (bytes + 255) & ~(size_t)255;
        return p;
    };
    unsigned short* Abf = (unsigned short*)alloc((size_t)BS_ * E_ * 2);
    unsigned short* Wqt = (unsigned short*)alloc((size_t)H_ * D_ * E_ * 2);
    unsigned short* Wkt = (unsigned short*)alloc((size_t)H_ * D_ * E_ * 2);
    unsigned short* Wvt = (unsigned short*)alloc((size_t)H_ * D_ * E_ * 2);
    unsigned short* Wzt = (unsigned short*)alloc((size_t)E_ * HD_ * 2);
    unsigned short* Qb = (unsigned short*)alloc((size_t)BH_ * S_ * D_ * 2);
    unsigned short* Kb = (unsigned short*)alloc((size_t)BH_ * S_ * D_ * 2);
    unsigned short* Vb = (unsigned short*)alloc((size_t)BH_ * S_ * D_ * 2);
    unsigned short* Vtb = (unsigned short*)alloc((size_t)BH_ * S_ * D_ * 2);
    unsigned short* Zb = (unsigned short*)alloc((size_t)BS_ * HD_ * 2);
    float* Lc = (float*)alloc((size_t)BH_ * S_ * 4);

    dim3 tb(32, 8);
    cast_k<<<(BS_ * E_ / 4 + 255) / 256, 256, 0, stream>>>(Ain, Abf, BS_ * E_ / 4);
    tcast_k<<<dim3(D_ / 32, E_ / 32, H_), tb, 0, stream>>>(WQ, Wqt, E_, D_);
    tcast_k<<<dim3(D_ / 32, E_ / 32, H_), tb, 0, stream>>>(WK, Wkt, E_, D_);
    tcast_k<<<dim3(D_ / 32, E_ / 32, H_), tb, 0, stream>>>(WV, Wvt, E_, D_);
    tcast_k<<<dim3(E_ / 32, HD_ / 32, 1), tb, 0, stream>>>(WZ, Wzt, HD_, E_);

    gemm_qkv256_k<<<dim3((BS_ / 256) * (HD_ / 256)), 512, 0, stream>>>(Abf, Wqt, bQ, Qb);
    gemm_qkv256_k<<<dim3((BS_ / 256) * (HD_ / 256)), 512, 0, stream>>>(Abf, Wkt, bK, Kb);
    gemm_qkv256_k<<<dim3((BS_ / 256) * (HD_ / 256)), 512, 0, stream>>>(Abf, Wvt, bV, Vb);

    tbf_k<<<dim3(D_ / 32, S_ / 32, BH_), tb, 0, stream>>>(Vb, Vtb);

    colsum_k<<<dim3(BH_ * S_ / 128), 512, 0, stream>>>(Qb, Kb, Lc);
    flash12_k<<<dim3(BH_ * S_ / 128), 256, 0, stream>>>(Qb, Kb, Vtb, Lc, Zb);

    gemm_out_k<<<dim3(E_ / 128, BS_ / 128), 256, 0, stream>>>(Zb, Wzt, bZ, out);
}